// Round 8
// baseline (38294.531 us; speedup 1.0000x reference)
//
#include <hip/hip_runtime.h>
#include <hip/hip_bf16.h>
#include <cmath>

typedef __hip_bfloat16 bf16;

#define SEQ   2048
#define DIMX  512
#define DIM2X 1024
#define NHEADS 8
#define HDIM  128
#define EPSF  1e-5f

__device__ __forceinline__ float b2f(bf16 v) { return __bfloat162float(v); }
__device__ __forceinline__ bf16 f2b(float f) { return __float2bfloat16(f); }
__device__ __forceinline__ float satexp(float x) { return expf(fminf(x, 30.f)); }

// ---------------- LayerNorm: one thread per row ----------------
__global__ void __launch_bounds__(256) n_ln(const float* __restrict__ x,
                                            const float* __restrict__ w,
                                            const float* __restrict__ b,
                                            bf16* __restrict__ out) {
  int row = blockIdx.x * 256 + threadIdx.x;
  if (row >= 4096) return;
  const float* xr = x + (size_t)row * DIMX;
  float s = 0.f;
  for (int k = 0; k < DIMX; k++) s += xr[k];
  float mu = s / DIMX;
  float v = 0.f;
  for (int k = 0; k < DIMX; k++) { float d = xr[k] - mu; v += d * d; }
  float rs = rsqrtf(v / DIMX + EPSF);
  bf16* o = out + (size_t)row * DIMX;
  for (int k = 0; k < DIMX; k++) o[k] = f2b((xr[k] - mu) * rs * w[k] + b[k]);
}

// ---------------- naive GEMM (bf16 out): C = act(A@W + bias) ----------------
template <int ACT>
__global__ void __launch_bounds__(256) n_gemm(const bf16* __restrict__ A,
                                              const float* __restrict__ W,
                                              const float* __restrict__ bias,
                                              bf16* __restrict__ C, int N, int K) {
  int idx = blockIdx.x * 256 + threadIdx.x;   // m*N + n
  int m = idx / N, n = idx - m * N;
  float s = bias ? bias[n] : 0.f;
  const bf16* ar = A + (size_t)m * K;
  const float* wc = W + n;
  for (int k = 0; k < K; k++) s += b2f(ar[k]) * wc[(size_t)k * N];
  if (ACT) s = s / (1.f + expf(-s));  // silu
  C[idx] = f2b(s);
}

// ---------------- FINAL GEMM: fp32 OUTPUT. out = x + pre@fin_w + fin_b ----------------
__global__ void __launch_bounds__(256) n_gemm_out(const bf16* __restrict__ A,
                                                  const float* __restrict__ W,
                                                  const float* __restrict__ bias,
                                                  const float* __restrict__ xres,
                                                  float* __restrict__ out) {
  int idx = blockIdx.x * 256 + threadIdx.x;   // m*512 + n
  int m = idx >> 9, n = idx & 511;
  float s = bias[n];
  const bf16* ar = A + (size_t)m * DIM2X;
  const float* wc = W + n;
  for (int k = 0; k < DIM2X; k++) s += b2f(ar[k]) * wc[(size_t)k * DIMX];
  out[idx] = xres[idx] + s;
}

// ---------------- naive causal conv1d + silu, conv_w native (O,I,KS) layout ----------------
__global__ void __launch_bounds__(256) n_conv(const bf16* __restrict__ a,
                                              const float* __restrict__ cw,
                                              const float* __restrict__ cb,
                                              bf16* __restrict__ qk) {
  int idx = blockIdx.x * 256 + threadIdx.x;   // m*1024 + o
  int m = idx >> 10, o = idx & 1023;
  int b = m >> 11, t = m & 2047;
  float s = cb[o];
  const float* w = cw + (size_t)o * 4096;     // w[o][i][kk] strides (4096,4,1)
  for (int kk = 0; kk < 4; kk++) {
    int ts = t - 3 + kk;
    if (ts < 0) continue;
    const bf16* ar = a + ((size_t)(b * 2048 + ts)) * DIM2X;
    for (int i = 0; i < 1024; i++) s += b2f(ar[i]) * w[i * 4 + kk];
  }
  s = s / (1.f + expf(-s));  // silu
  qk[idx] = f2b(s);
}

// ---------------- naive block-diagonal linear ----------------
__global__ void __launch_bounds__(256) n_blockdiag(const bf16* __restrict__ X,
                                                   const float* __restrict__ W,
                                                   bf16* __restrict__ Y) {
  int idx = blockIdx.x * 256 + threadIdx.x;   // m*1024 + c
  int m = idx >> 10, c = idx & 1023, g = c >> 8, o = c & 255;
  const bf16* xr = X + (size_t)m * DIM2X + g * 256;
  const float* w = W + (size_t)g * 65536 + o;
  float s = 0.f;
  for (int i = 0; i < 256; i++) s += b2f(xr[i]) * w[(size_t)i * 256];
  Y[idx] = f2b(s);
}

// ---------------- naive gates: it[b,h,s] = q·wi[:,h]+wib ; ft = k·wf[:,h]+wfb ----------------
__global__ void __launch_bounds__(256) n_gates(const bf16* __restrict__ q, const bf16* __restrict__ k,
                                               const float* __restrict__ wi, const float* __restrict__ wib,
                                               const float* __restrict__ wf, const float* __restrict__ wfb,
                                               float* __restrict__ it, float* __restrict__ ft) {
  int idx = blockIdx.x * 256 + threadIdx.x;   // which*32768 + m*8 + h
  int which = idx >> 15;
  int m = (idx >> 3) & 4095, h = idx & 7;
  const bf16* row = (which ? k : q) + (size_t)m * DIM2X;
  const float* w = (which ? wf : wi) + h;
  float s = (which ? wfb : wib)[h];
  for (int d = 0; d < DIM2X; d++) s += b2f(row[d]) * w[d * 8];
  int b = m >> 11, t = m & 2047;
  (which ? ft : it)[(size_t)(b * 8 + h) * SEQ + t] = s;
}

// ---------------- fully serial scan per (b,h) ----------------
__global__ void __launch_bounds__(64) n_scan(const float* __restrict__ it, const float* __restrict__ ft,
                                             float* __restrict__ cs, float* __restrict__ md) {
  int bh = threadIdx.x;
  if (bh >= 16) return;
  const float* fr = ft + (size_t)bh * SEQ;
  const float* ir = it + (size_t)bh * SEQ;
  float* csr = cs + (size_t)bh * SEQ;
  float* mdr = md + (size_t)bh * SEQ;
  float run = 0.f, mx = -INFINITY;
  for (int t = 0; t < SEQ; t++) {
    float xv = fr[t];
    run += fminf(xv, 0.f) - log1pf(expf(-fabsf(xv)));  // stable log_sigmoid
    csr[t] = run;
    mx = fmaxf(mx, ir[t] - run);
    mdr[t] = run + mx;
  }
}

// ---------------- naive attention: block per (bh,i), thread per column ----------------
__global__ void __launch_bounds__(128) n_attn(const bf16* __restrict__ qh, const bf16* __restrict__ kh,
                                              const bf16* __restrict__ vh,
                                              const float* __restrict__ cs, const float* __restrict__ md,
                                              const float* __restrict__ itl,
                                              bf16* __restrict__ H) {
  const int i  = blockIdx.x;       // 0..2047
  const int bh = blockIdx.y;       // 0..15
  const int b  = bh >> 3, h = bh & 7;
  const int d  = threadIdx.x;      // 0..127
  __shared__ float qs[128], sv[128], red[128];
  const size_t base = ((size_t)b * SEQ) * DIM2X + (size_t)h * HDIM;
  qs[d] = b2f(qh[base + (size_t)i * DIM2X + d]);
  __syncthreads();
  const float cs_i = cs[(size_t)bh * SEQ + i];
  const float md_i = md[(size_t)bh * SEQ + i];
  float accH = 0.f, rs_p = 0.f;
  for (int j0 = 0; j0 <= i; j0 += 128) {
    int j = j0 + d;
    float sval = 0.f;
    if (j <= i) {
      const bf16* kr = kh + base + (size_t)j * DIM2X;
      float dot = 0.f;
      for (int e = 0; e < HDIM; e++) dot += qs[e] * b2f(kr[e]);
      sval = satexp(cs_i - cs[(size_t)bh * SEQ + j] + itl[(size_t)bh * SEQ + j] - md_i)
             * dot * (1.f / 32.f);
    }
    rs_p += sval;
    sv[d] = sval;
    __syncthreads();
    for (int jj = 0; jj < 128; jj++) {
      if (j0 + jj > i) break;
      accH += sv[jj] * b2f(vh[base + (size_t)(j0 + jj) * DIM2X + d]);
    }
    __syncthreads();
  }
  red[d] = rs_p;
  __syncthreads();
  for (int off = 64; off; off >>= 1) {
    if (d < off) red[d] += red[d + off];
    __syncthreads();
  }
  float rsum = red[0];
  float maxit = fmaxf(fabsf(rsum), satexp(-md_i));
  H[base + (size_t)i * DIM2X + d] = f2b(accH / (maxit + 1e-8f));
}

// ---------------- naive GroupNorm(per (m,h) over 128) + skip*qk then *bgate ----------------
__global__ void __launch_bounds__(256) n_gnorm(const bf16* __restrict__ H, const bf16* __restrict__ qk,
                                               const bf16* __restrict__ bg,
                                               const float* __restrict__ gw, const float* __restrict__ gb,
                                               const float* __restrict__ skip, bf16* __restrict__ pre) {
  int idx = blockIdx.x * 256 + threadIdx.x;   // m*8 + h
  int m = idx >> 3, h = idx & 7;
  const bf16* Hr = H + (size_t)m * DIM2X + (size_t)h * HDIM;
  float s = 0.f;
  for (int c = 0; c < HDIM; c++) s += b2f(Hr[c]);
  float mu = s / HDIM;
  float v = 0.f;
  for (int c = 0; c < HDIM; c++) { float dd = b2f(Hr[c]) - mu; v += dd * dd; }
  float rs = rsqrtf(v / HDIM + EPSF);
  for (int c = 0; c < HDIM; c++) {
    int col = h * HDIM + c;
    size_t g = (size_t)m * DIM2X + col;
    float hn = (b2f(Hr[c]) - mu) * rs * gw[col] + gb[col];
    pre[g] = f2b((hn + skip[col] * b2f(qk[g])) * b2f(bg[g]));
  }
}

extern "C" void kernel_launch(void* const* d_in, const int* in_sizes, int n_in,
                              void* d_out, int out_size, void* d_ws, size_t ws_size,
                              hipStream_t stream) {
  const float* x     = (const float*)d_in[0];
  const float* ln_w  = (const float*)d_in[1];
  const float* ln_b  = (const float*)d_in[2];
  const float* mlp1w = (const float*)d_in[3];
  const float* mlp1b = (const float*)d_in[4];
  const float* mlp2w = (const float*)d_in[5];
  const float* mlp2b = (const float*)d_in[6];
  const float* convw = (const float*)d_in[7];
  const float* convb = (const float*)d_in[8];
  const float* bqw   = (const float*)d_in[9];
  const float* bkw   = (const float*)d_in[10];
  const float* bvw   = (const float*)d_in[11];
  const float* wqw   = (const float*)d_in[12];
  const float* wqb   = (const float*)d_in[13];
  const float* wkw   = (const float*)d_in[14];
  const float* wkb   = (const float*)d_in[15];
  const float* wvw   = (const float*)d_in[16];
  const float* wvb   = (const float*)d_in[17];
  const float* wiw   = (const float*)d_in[18];
  const float* wib   = (const float*)d_in[19];
  const float* wfw   = (const float*)d_in[20];
  const float* wfb   = (const float*)d_in[21];
  const float* gnw   = (const float*)d_in[22];
  const float* gnb   = (const float*)d_in[23];
  const float* skip  = (const float*)d_in[24];
  const float* finw  = (const float*)d_in[25];
  const float* finb  = (const float*)d_in[26];
  float* out = (float*)d_out;   // <-- fp32 OUTPUT (reference returns float32)

  // ---- workspace: gates first (512KB+), then 7 recycled 4M-elem bf16 slots (57MB total) ----
  float* GA  = (float*)d_ws;
  float* ITb = GA;
  float* FTb = GA + 32768;
  float* CSb = GA + 65536;
  float* MDb = GA + 98304;
  const size_t SLOT = 4u * 1024u * 1024u;
  bf16* S0 = (bf16*)((char*)d_ws + (1 << 20));
  bf16* S1 = S0 + SLOT;
  bf16* S2 = S1 + SLOT;
  bf16* S3 = S2 + SLOT;
  bf16* S4 = S3 + SLOT;
  bf16* S5 = S4 + SLOT;
  bf16* S6 = S5 + SLOT;
  bf16 *LN = S0, *A_ = S1, *BG = S2, *QKb = S3, *Qb = S4, *Kb = S5, *Vb = S6;
  bf16 *QH = S0, *KH = S1, *VH = S4, *Hb = S5, *PRE = S6;  // recycled (liveness-checked)

  n_ln<<<16, 256, 0, stream>>>(x, ln_w, ln_b, LN);
  n_gemm<0><<<16384, 256, 0, stream>>>(LN, mlp1w, mlp1b, A_, DIM2X, DIMX);
  n_gemm<1><<<16384, 256, 0, stream>>>(LN, mlp2w, mlp2b, BG, DIM2X, DIMX);
  n_conv<<<16384, 256, 0, stream>>>(A_, convw, convb, QKb);
  n_blockdiag<<<16384, 256, 0, stream>>>(QKb, bqw, Qb);
  n_blockdiag<<<16384, 256, 0, stream>>>(QKb, bkw, Kb);
  n_blockdiag<<<16384, 256, 0, stream>>>(A_, bvw, Vb);
  n_gates<<<256, 256, 0, stream>>>(Qb, Kb, wiw, wib, wfw, wfb, ITb, FTb);
  n_scan<<<1, 64, 0, stream>>>(ITb, FTb, CSb, MDb);
  n_gemm<0><<<16384, 256, 0, stream>>>(Qb, wqw, wqb, QH, DIM2X, DIM2X);
  n_gemm<0><<<16384, 256, 0, stream>>>(Kb, wkw, wkb, KH, DIM2X, DIM2X);
  n_gemm<0><<<16384, 256, 0, stream>>>(Vb, wvw, wvb, VH, DIM2X, DIM2X);
  n_attn<<<dim3(2048, 16), 128, 0, stream>>>(QH, KH, VH, CSb, MDb, ITb, Hb);
  n_gnorm<<<128, 256, 0, stream>>>(Hb, QKb, BG, gnw, gnb, skip, PRE);
  n_gemm_out<<<8192, 256, 0, stream>>>(PRE, finw, finb, x, out);
}

// Round 9
// 2576.079 us; speedup vs baseline: 14.8654x; 14.8654x over previous
//
#include <hip/hip_runtime.h>
#include <hip/hip_bf16.h>
#include <cmath>

typedef __hip_bfloat16 bf16;

#define SEQ   2048
#define DIMX  512
#define DIM2X 1024
#define NHEADS 8
#define HDIM  128
#define EPSF  1e-5f

__device__ __forceinline__ float b2f(bf16 v) { return __bfloat162float(v); }
__device__ __forceinline__ bf16 f2b(float f) { return __float2bfloat16(f); }
__device__ __forceinline__ float bits2f(unsigned int lo16) { return __uint_as_float(lo16 << 16); }
__device__ __forceinline__ float satexp(float x) { return expf(fminf(x, 30.f)); }

__device__ __forceinline__ void st8(float* dst, uint4 u) {
  dst[0] = bits2f(u.x & 0xffffu); dst[1] = bits2f(u.x >> 16);
  dst[2] = bits2f(u.y & 0xffffu); dst[3] = bits2f(u.y >> 16);
  dst[4] = bits2f(u.z & 0xffffu); dst[5] = bits2f(u.z >> 16);
  dst[6] = bits2f(u.w & 0xffffu); dst[7] = bits2f(u.w >> 16);
}

// ---------------- LayerNorm: one wave per row of 512 (fp32 in, bf16 out) ----------------
__global__ void __launch_bounds__(256) k_layernorm(const float* __restrict__ x,
                                                   const float* __restrict__ w,
                                                   const float* __restrict__ b,
                                                   bf16* __restrict__ out) {
  int row  = blockIdx.x * 4 + (threadIdx.x >> 6);
  int lane = threadIdx.x & 63;
  const float* xr = x + (size_t)row * DIMX;
  float v[8]; float s = 0.f, sq = 0.f;
#pragma unroll
  for (int i = 0; i < 8; i++) {
    float f = xr[lane + i * 64];
    v[i] = f; s += f; sq += f * f;
  }
#pragma unroll
  for (int off = 32; off; off >>= 1) { s += __shfl_xor(s, off); sq += __shfl_xor(sq, off); }
  float mu  = s * (1.f / DIMX);
  float var = sq * (1.f / DIMX) - mu * mu;
  float rs  = rsqrtf(var + EPSF);
  bf16* o = out + (size_t)row * DIMX;
#pragma unroll
  for (int i = 0; i < 8; i++) {
    int c = lane + i * 64;
    o[c] = f2b((v[i] - mu) * rs * w[c] + b[c]);
  }
}

#define FMA16 \
  acc[0][0] += a4.x*w4.x; acc[0][1] += a4.x*w4.y; acc[0][2] += a4.x*w4.z; acc[0][3] += a4.x*w4.w; \
  acc[1][0] += a4.y*w4.x; acc[1][1] += a4.y*w4.y; acc[1][2] += a4.y*w4.z; acc[1][3] += a4.y*w4.w; \
  acc[2][0] += a4.z*w4.x; acc[2][1] += a4.z*w4.y; acc[2][2] += a4.z*w4.z; acc[2][3] += a4.z*w4.w; \
  acc[3][0] += a4.w*w4.x; acc[3][1] += a4.w*w4.y; acc[3][2] += a4.w*w4.z; acc[3][3] += a4.w*w4.w;

// ---------------- Tiled GEMM: C(bf16) = act(A(bf16)@W(fp32) + bias) ----------------
// 64x64 tile, BK=16, 4x4/thread. blockIdx.z batching via gA/gW/gC element strides.
template <int ACT>
__global__ void __launch_bounds__(256) k_gemm(const bf16* __restrict__ A, int lda,
                                              const float* __restrict__ W, int ldw,
                                              const float* __restrict__ bias,
                                              bf16* __restrict__ C, int ldc, int K,
                                              int gA, int gW, int gC) {
  __shared__ float As[16][64];
  __shared__ float Ws[16][64];
  const int g = blockIdx.z;
  A += (size_t)g * gA; W += (size_t)g * gW; C += (size_t)g * gC;
  const int tx = threadIdx.x & 15, ty = threadIdx.x >> 4;
  const int bm = blockIdx.y * 64, bn = blockIdx.x * 64;
  const int lr = threadIdx.x >> 2;
  const int lc = (threadIdx.x & 3) * 4;
  const int wr = threadIdx.x >> 4;
  const int wc = (threadIdx.x & 15) * 4;
  float acc[4][4] = {};
  for (int k0 = 0; k0 < K; k0 += 16) {
    ushort4 av = *(const ushort4*)(A + (size_t)(bm + lr) * lda + k0 + lc);
    As[lc + 0][lr] = bits2f(av.x); As[lc + 1][lr] = bits2f(av.y);
    As[lc + 2][lr] = bits2f(av.z); As[lc + 3][lr] = bits2f(av.w);
    float4 wv = *(const float4*)(W + (size_t)(k0 + wr) * ldw + bn + wc);
    Ws[wr][wc + 0] = wv.x; Ws[wr][wc + 1] = wv.y; Ws[wr][wc + 2] = wv.z; Ws[wr][wc + 3] = wv.w;
    __syncthreads();
#pragma unroll
    for (int kk = 0; kk < 16; kk++) {
      float4 a4 = *(const float4*)&As[kk][ty * 4];
      float4 w4 = *(const float4*)&Ws[kk][tx * 4];
      FMA16
    }
    __syncthreads();
  }
#pragma unroll
  for (int i = 0; i < 4; i++) {
    int row = bm + ty * 4 + i;
#pragma unroll
    for (int j = 0; j < 4; j++) {
      int col = bn + tx * 4 + j;
      float v = acc[i][j];
      if (bias) v += bias[col];
      if (ACT == 1) v = v / (1.f + expf(-v));  // silu
      C[(size_t)row * ldc + col] = f2b(v);
    }
  }
}

// ---------------- conv weight transpose: WC[kk][i][o] = conv_w[o][i][kk] (fp32 -> bf16) ----------------
__global__ void __launch_bounds__(256) k_convw(const float* __restrict__ cw, bf16* __restrict__ wc) {
  int idx = blockIdx.x * 256 + threadIdx.x;   // enumerates (o,i,kk) in input order
  int kk = idx & 3;
  int i  = (idx >> 2) & 1023;
  int o  = idx >> 12;
  wc[((size_t)kk << 20) + ((size_t)i << 10) + o] = f2b(cw[idx]);
}

// ---------------- causal conv1d as 4 shifted GEMMs, fused silu ----------------
__global__ void __launch_bounds__(256) k_conv(const bf16* __restrict__ a,
                                              const bf16* __restrict__ wcw,
                                              const float* __restrict__ cb,
                                              bf16* __restrict__ qk) {
  __shared__ float As[16][64];
  __shared__ float Ws[16][64];
  const int tx = threadIdx.x & 15, ty = threadIdx.x >> 4;
  const int bm = blockIdx.y * 64, bn = blockIdx.x * 64;
  const int lr = threadIdx.x >> 2;
  const int lc = (threadIdx.x & 3) * 4;
  const int wr = threadIdx.x >> 4;
  const int wc = (threadIdx.x & 15) * 4;
  const int m = bm + lr;
  const int b_ = m >> 11, t = m & 2047;
  float acc[4][4] = {};
  for (int kk = 0; kk < 4; kk++) {
    const int ts = t - 3 + kk;
    const bf16* arow = a + ((size_t)(b_ << 11) + ts) * DIM2X;
    const bf16* wbase = wcw + ((size_t)kk << 20);
    for (int k0 = 0; k0 < DIM2X; k0 += 16) {
      float a0 = 0.f, a1 = 0.f, a2 = 0.f, a3 = 0.f;
      if (ts >= 0) {
        ushort4 av = *(const ushort4*)(arow + k0 + lc);
        a0 = bits2f(av.x); a1 = bits2f(av.y); a2 = bits2f(av.z); a3 = bits2f(av.w);
      }
      As[lc + 0][lr] = a0; As[lc + 1][lr] = a1; As[lc + 2][lr] = a2; As[lc + 3][lr] = a3;
      ushort4 wv = *(const ushort4*)(wbase + (size_t)(k0 + wr) * DIM2X + bn + wc);
      Ws[wr][wc + 0] = bits2f(wv.x); Ws[wr][wc + 1] = bits2f(wv.y);
      Ws[wr][wc + 2] = bits2f(wv.z); Ws[wr][wc + 3] = bits2f(wv.w);
      __syncthreads();
#pragma unroll
      for (int kx = 0; kx < 16; kx++) {
        float4 a4 = *(const float4*)&As[kx][ty * 4];
        float4 w4 = *(const float4*)&Ws[kx][tx * 4];
        FMA16
      }
      __syncthreads();
    }
  }
#pragma unroll
  for (int i = 0; i < 4; i++) {
    int row = bm + ty * 4 + i;
#pragma unroll
    for (int j = 0; j < 4; j++) {
      int col = bn + tx * 4 + j;
      float v = acc[i][j] + cb[col];
      v = v / (1.f + expf(-v));  // silu
      qk[(size_t)row * DIM2X + col] = f2b(v);
    }
  }
}

// ---------------- gate GEMV: it = q@wi + wib ; ft = k@wf + wfb ([b,h,s] fp32 out) ----------------
__global__ void __launch_bounds__(256) k_gates(const bf16* __restrict__ q, const bf16* __restrict__ kk,
                                               const float* __restrict__ wi, const float* __restrict__ wib,
                                               const float* __restrict__ wf, const float* __restrict__ wfb,
                                               float* __restrict__ it, float* __restrict__ ft) {
  int gid  = blockIdx.x * 4 + (threadIdx.x >> 6);  // 0..8191 = which*4096 + m
  int lane = threadIdx.x & 63;
  int which = gid >> 12;
  int m = gid & 4095;
  const bf16* row = (which ? kk : q) + (size_t)m * DIM2X;
  const float* w = which ? wf : wi;
  float s[8] = {0, 0, 0, 0, 0, 0, 0, 0};
  for (int d = lane; d < DIM2X; d += 64) {
    float xv = b2f(row[d]);
    const float4* wp = (const float4*)(w + d * 8);
    float4 w0 = wp[0], w1 = wp[1];
    s[0] += xv * w0.x; s[1] += xv * w0.y; s[2] += xv * w0.z; s[3] += xv * w0.w;
    s[4] += xv * w1.x; s[5] += xv * w1.y; s[6] += xv * w1.z; s[7] += xv * w1.w;
  }
#pragma unroll
  for (int off = 32; off; off >>= 1) {
#pragma unroll
    for (int h = 0; h < 8; h++) s[h] += __shfl_xor(s[h], off);
  }
  if (lane == 0) {
    int b_ = m >> 11, tt = m & 2047;
    const float* wb = which ? wfb : wib;
    float* dst = which ? ft : it;
#pragma unroll
    for (int h = 0; h < 8; h++)
      dst[((size_t)(b_ * NHEADS + h)) * SEQ + tt] = s[h] + wb[h];
  }
}

// ---------------- per-(b,h) scan: cs = cumsum(logsigmoid(ft)); md = cs + prefmax(it - cs) ----------------
__global__ void __launch_bounds__(256) k_scan(const float* __restrict__ it, const float* __restrict__ ft,
                                              float* __restrict__ cs, float* __restrict__ md) {
  const int bh = blockIdx.x;
  const int t  = threadIdx.x;  // 256 threads, 8 elems each
  const float* fr = ft + (size_t)bh * SEQ;
  const float* ir = it + (size_t)bh * SEQ;
  float* csr = cs + (size_t)bh * SEQ;
  float* mdr = md + (size_t)bh * SEQ;
  __shared__ float tmp[256];
  float loc[8]; float run = 0.f;
#pragma unroll
  for (int j = 0; j < 8; j++) {
    float xv = fr[t * 8 + j];
    float ls = fminf(xv, 0.f) - log1pf(expf(-fabsf(xv)));  // stable log_sigmoid
    run += ls; loc[j] = run;
  }
  tmp[t] = run;
  __syncthreads();
  for (int off = 1; off < 256; off <<= 1) {
    float add = (t >= off) ? tmp[t - off] : 0.f;
    __syncthreads();
    tmp[t] += add;
    __syncthreads();
  }
  float exc = (t == 0) ? 0.f : tmp[t - 1];
  float csv[8];
#pragma unroll
  for (int j = 0; j < 8; j++) { csv[j] = loc[j] + exc; csr[t * 8 + j] = csv[j]; }
  __syncthreads();
  float rmax = -INFINITY; float gm[8];
#pragma unroll
  for (int j = 0; j < 8; j++) {
    float gv = ir[t * 8 + j] - csv[j];
    rmax = fmaxf(rmax, gv); gm[j] = rmax;
  }
  tmp[t] = rmax;
  __syncthreads();
  for (int off = 1; off < 256; off <<= 1) {
    float other = (t >= off) ? tmp[t - off] : -INFINITY;
    __syncthreads();
    tmp[t] = fmaxf(tmp[t], other);
    __syncthreads();
  }
  float emax = (t == 0) ? -INFINITY : tmp[t - 1];
#pragma unroll
  for (int j = 0; j < 8; j++) mdr[t * 8 + j] = csv[j] + fmaxf(gm[j], emax);
}

// ---------------- tiled causal attention: 16x16 tiles, md precomputed (no online rescale) ----------------
__global__ void __launch_bounds__(256) k_attn(const bf16* __restrict__ qh, const bf16* __restrict__ kh,
                                              const bf16* __restrict__ vh,
                                              const float* __restrict__ cs, const float* __restrict__ md,
                                              const float* __restrict__ itl,
                                              bf16* __restrict__ Hout) {
  const int bh = blockIdx.y;
  const int b_ = bh >> 3, h = bh & 7;
  const int i0 = blockIdx.x * 16;
  const int tx = threadIdx.x & 15, ty = threadIdx.x >> 4;
  __shared__ float Q[16][130];
  __shared__ float Kt[16][130];
  __shared__ float V[16][130];
  __shared__ float Sc[16][16];
  const size_t base = ((size_t)b_ * SEQ) * DIM2X + (size_t)h * HDIM;
  {
    uint4 qv = *(const uint4*)(qh + base + (size_t)(i0 + ty) * DIM2X + tx * 8);
    st8(&Q[ty][tx * 8], qv);
  }
  const float* csp = cs + (size_t)bh * SEQ;
  const float* mdp = md + (size_t)bh * SEQ;
  const float* itp = itl + (size_t)bh * SEQ;
  const int i = i0 + ty;
  const float cs_i = csp[i];
  const float md_i = mdp[i];
  float accH[8] = {};
  float rs_part = 0.f;
  for (int j0 = 0; j0 <= i0; j0 += 16) {
    __syncthreads();
    {
      size_t g = base + (size_t)(j0 + ty) * DIM2X + tx * 8;
      uint4 kv = *(const uint4*)(kh + g);
      uint4 vv = *(const uint4*)(vh + g);
      st8(&Kt[ty][tx * 8], kv);
      st8(&V[ty][tx * 8], vv);
    }
    __syncthreads();
    float dot = 0.f;
#pragma unroll 16
    for (int d = 0; d < 128; d++) dot += Q[ty][d] * Kt[tx][d];
    int j = j0 + tx;
    float sval = 0.f;
    if (j <= i) sval = satexp(cs_i - csp[j] + itp[j] - md_i) * dot * (1.f / 32.f);
    rs_part += sval;
    Sc[ty][tx] = sval;
    __syncthreads();
#pragma unroll
    for (int jj = 0; jj < 16; jj++) {
      float sv = Sc[ty][jj];
#pragma unroll
      for (int c = 0; c < 8; c++) accH[c] += sv * V[jj][tx + c * 16];
    }
  }
  float rsum = rs_part;
  rsum += __shfl_xor(rsum, 1); rsum += __shfl_xor(rsum, 2);
  rsum += __shfl_xor(rsum, 4); rsum += __shfl_xor(rsum, 8);
  float maxit = fmaxf(fabsf(rsum), satexp(-md_i));
  float inv = 1.f / (maxit + 1e-8f);
  size_t ho = base + (size_t)i * DIM2X;
#pragma unroll
  for (int c = 0; c < 8; c++) Hout[ho + tx + c * 16] = f2b(accH[c] * inv);
}

// ---------------- GroupNorm(per-head over 128) + skip*qk then *bgate ----------------
__global__ void __launch_bounds__(256) k_gnorm(const bf16* __restrict__ H, const bf16* __restrict__ qk,
                                               const bf16* __restrict__ bg,
                                               const float* __restrict__ gw, const float* __restrict__ gb,
                                               const float* __restrict__ skip, bf16* __restrict__ pre) {
  int gid  = blockIdx.x * 4 + (threadIdx.x >> 6);  // (m,h)
  int lane = threadIdx.x & 63;
  int m = gid >> 3, h = gid & 7;
  const bf16* Hr = H + (size_t)m * DIM2X + (size_t)h * HDIM;
  float v0 = b2f(Hr[lane]), v1 = b2f(Hr[lane + 64]);
  float s = v0 + v1, sq = v0 * v0 + v1 * v1;
#pragma unroll
  for (int off = 32; off; off >>= 1) { s += __shfl_xor(s, off); sq += __shfl_xor(sq, off); }
  float mu  = s * (1.f / 128.f);
  float var = sq * (1.f / 128.f) - mu * mu;
  float rs  = rsqrtf(var + EPSF);
#pragma unroll
  for (int e = 0; e < 2; e++) {
    int c = lane + e * 64;
    int col = h * HDIM + c;
    float v = e ? v1 : v0;
    float hn = (v - mu) * rs * gw[col] + gb[col];
    size_t gidx = (size_t)m * DIM2X + col;
    pre[gidx] = f2b((hn + skip[col] * b2f(qk[gidx])) * b2f(bg[gidx]));
  }
}

// ---------------- final tiled GEMM: out(fp32) = x + pre@fin_w + fin_b ----------------
__global__ void __launch_bounds__(256) k_gemm_final(const bf16* __restrict__ A,
                                                    const float* __restrict__ W,
                                                    const float* __restrict__ bias,
                                                    const float* __restrict__ xres,
                                                    float* __restrict__ out) {
  __shared__ float As[16][64];
  __shared__ float Ws[16][64];
  const int tx = threadIdx.x & 15, ty = threadIdx.x >> 4;
  const int bm = blockIdx.y * 64, bn = blockIdx.x * 64;
  const int lr = threadIdx.x >> 2;
  const int lc = (threadIdx.x & 3) * 4;
  const int wr = threadIdx.x >> 4;
  const int wc = (threadIdx.x & 15) * 4;
  float acc[4][4] = {};
  for (int k0 = 0; k0 < DIM2X; k0 += 16) {
    ushort4 av = *(const ushort4*)(A + (size_t)(bm + lr) * DIM2X + k0 + lc);
    As[lc + 0][lr] = bits2f(av.x); As[lc + 1][lr] = bits2f(av.y);
    As[lc + 2][lr] = bits2f(av.z); As[lc + 3][lr] = bits2f(av.w);
    float4 wv = *(const float4*)(W + (size_t)(k0 + wr) * DIMX + bn + wc);
    Ws[wr][wc + 0] = wv.x; Ws[wr][wc + 1] = wv.y; Ws[wr][wc + 2] = wv.z; Ws[wr][wc + 3] = wv.w;
    __syncthreads();
#pragma unroll
    for (int kk = 0; kk < 16; kk++) {
      float4 a4 = *(const float4*)&As[kk][ty * 4];
      float4 w4 = *(const float4*)&Ws[kk][tx * 4];
      FMA16
    }
    __syncthreads();
  }
#pragma unroll
  for (int i = 0; i < 4; i++) {
    int row = bm + ty * 4 + i;
#pragma unroll
    for (int j = 0; j < 4; j++) {
      int col = bn + tx * 4 + j;
      size_t gidx = (size_t)row * DIMX + col;
      out[gidx] = acc[i][j] + bias[col] + xres[gidx];
    }
  }
}

extern "C" void kernel_launch(void* const* d_in, const int* in_sizes, int n_in,
                              void* d_out, int out_size, void* d_ws, size_t ws_size,
                              hipStream_t stream) {
  const float* x     = (const float*)d_in[0];
  const float* ln_w  = (const float*)d_in[1];
  const float* ln_b  = (const float*)d_in[2];
  const float* mlp1w = (const float*)d_in[3];
  const float* mlp1b = (const float*)d_in[4];
  const float* mlp2w = (const float*)d_in[5];
  const float* mlp2b = (const float*)d_in[6];
  const float* convw = (const float*)d_in[7];
  const float* convb = (const float*)d_in[8];
  const float* bqw   = (const float*)d_in[9];
  const float* bkw   = (const float*)d_in[10];
  const float* bvw   = (const float*)d_in[11];
  const float* wqw   = (const float*)d_in[12];
  const float* wqb   = (const float*)d_in[13];
  const float* wkw   = (const float*)d_in[14];
  const float* wkb   = (const float*)d_in[15];
  const float* wvw   = (const float*)d_in[16];
  const float* wvb   = (const float*)d_in[17];
  const float* wiw   = (const float*)d_in[18];
  const float* wib   = (const float*)d_in[19];
  const float* wfw   = (const float*)d_in[20];
  const float* wfb   = (const float*)d_in[21];
  const float* gnw   = (const float*)d_in[22];
  const float* gnb   = (const float*)d_in[23];
  const float* skip  = (const float*)d_in[24];
  const float* finw  = (const float*)d_in[25];
  const float* finb  = (const float*)d_in[26];
  float* out = (float*)d_out;   // fp32 output (verified round 8)

  // ---- workspace: gates first (512KB+), then 7 recycled 4M-elem bf16 slots (57MB) ----
  float* GA  = (float*)d_ws;
  float* ITb = GA;
  float* FTb = GA + 32768;
  float* CSb = GA + 65536;
  float* MDb = GA + 98304;
  const size_t SLOT = 4u * 1024u * 1024u;
  bf16* S0 = (bf16*)((char*)d_ws + (1 << 20));
  bf16* S1 = S0 + SLOT;
  bf16* S2 = S1 + SLOT;
  bf16* S3 = S2 + SLOT;
  bf16* S4 = S3 + SLOT;
  bf16* S5 = S4 + SLOT;
  bf16* S6 = S5 + SLOT;
  // liveness-checked recycling (journal): WC shares LN slot (LN dead after mlp2);
  // QH=S0 (WC dead), KH=S1 (A_ dead), VH=S4 (Qb dead), Hb=S5 (Kb dead), PRE=S6 (Vb dead)
  bf16 *LN = S0, *A_ = S1, *BG = S2, *QKb = S3, *Qb = S4, *Kb = S5, *Vb = S6;
  bf16 *WC = S0, *QH = S0, *KH = S1, *VH = S4, *Hb = S5, *PRE = S6;

  k_layernorm<<<1024, 256, 0, stream>>>(x, ln_w, ln_b, LN);
  k_gemm<0><<<dim3(16, 64), 256, 0, stream>>>(LN, DIMX, mlp1w, DIM2X, mlp1b, A_, DIM2X, DIMX, 0, 0, 0);
  k_gemm<1><<<dim3(16, 64), 256, 0, stream>>>(LN, DIMX, mlp2w, DIM2X, mlp2b, BG, DIM2X, DIMX, 0, 0, 0);
  k_convw<<<16384, 256, 0, stream>>>(convw, WC);
  k_conv<<<dim3(16, 64), 256, 0, stream>>>(A_, WC, convb, QKb);
  // block-diagonal linears, batched over 4 groups via blockIdx.z
  k_gemm<0><<<dim3(4, 64, 4), 256, 0, stream>>>(QKb, DIM2X, bqw, 256, nullptr, Qb, DIM2X, 256, 256, 65536, 256);
  k_gemm<0><<<dim3(4, 64, 4), 256, 0, stream>>>(QKb, DIM2X, bkw, 256, nullptr, Kb, DIM2X, 256, 256, 65536, 256);
  k_gemm<0><<<dim3(4, 64, 4), 256, 0, stream>>>(A_,  DIM2X, bvw, 256, nullptr, Vb, DIM2X, 256, 256, 65536, 256);
  k_gates<<<2048, 256, 0, stream>>>(Qb, Kb, wiw, wib, wfw, wfb, ITb, FTb);
  k_scan<<<16, 256, 0, stream>>>(ITb, FTb, CSb, MDb);
  k_gemm<0><<<dim3(16, 64), 256, 0, stream>>>(Qb, DIM2X, wqw, DIM2X, wqb, QH, DIM2X, DIM2X, 0, 0, 0);
  k_gemm<0><<<dim3(16, 64), 256, 0, stream>>>(Kb, DIM2X, wkw, DIM2X, wkb, KH, DIM2X, DIM2X, 0, 0, 0);
  k_gemm<0><<<dim3(16, 64), 256, 0, stream>>>(Vb, DIM2X, wvw, DIM2X, wvb, VH, DIM2X, DIM2X, 0, 0, 0);
  k_attn<<<dim3(128, 16), 256, 0, stream>>>(QH, KH, VH, CSb, MDb, ITb, Hb);
  k_gnorm<<<8192, 256, 0, stream>>>(Hb, QKb, BG, gnw, gnb, skip, PRE);
  k_gemm_final<<<dim3(8, 64), 256, 0, stream>>>(PRE, finw, finb, x, out);
}

// Round 10
// 1574.179 us; speedup vs baseline: 24.3267x; 1.6365x over previous
//
#include <hip/hip_runtime.h>
#include <hip/hip_bf16.h>
#include <cmath>

typedef __hip_bfloat16 bf16;
typedef __attribute__((ext_vector_type(8))) short short8;   // 8 bf16 (4 VGPRs)
typedef __attribute__((ext_vector_type(4))) float f32x4;

#define SEQ   2048
#define DIMX  512
#define DIM2X 1024
#define NHEADS 8
#define HDIM  128
#define EPSF  1e-5f

__device__ __forceinline__ float b2f(bf16 v) { return __bfloat162float(v); }
__device__ __forceinline__ bf16 f2b(float f) { return __float2bfloat16(f); }
__device__ __forceinline__ float bits2f(unsigned int lo16) { return __uint_as_float(lo16 << 16); }
__device__ __forceinline__ float satexp(float x) { return expf(fminf(x, 30.f)); }

// ---------------- LayerNorm: one wave per row of 512 (fp32 in, bf16 out) ----------------
__global__ void __launch_bounds__(256) k_layernorm(const float* __restrict__ x,
                                                   const float* __restrict__ w,
                                                   const float* __restrict__ b,
                                                   bf16* __restrict__ out) {
  int row  = blockIdx.x * 4 + (threadIdx.x >> 6);
  int lane = threadIdx.x & 63;
  const float* xr = x + (size_t)row * DIMX;
  float v[8]; float s = 0.f, sq = 0.f;
#pragma unroll
  for (int i = 0; i < 8; i++) {
    float f = xr[lane + i * 64];
    v[i] = f; s += f; sq += f * f;
  }
#pragma unroll
  for (int off = 32; off; off >>= 1) { s += __shfl_xor(s, off); sq += __shfl_xor(sq, off); }
  float mu  = s * (1.f / DIMX);
  float var = sq * (1.f / DIMX) - mu * mu;
  float rs  = rsqrtf(var + EPSF);
  bf16* o = out + (size_t)row * DIMX;
#pragma unroll
  for (int i = 0; i < 8; i++) {
    int c = lane + i * 64;
    o[c] = f2b((v[i] - mu) * rs * w[c] + b[c]);
  }
}

#define FMA16 \
  acc[0][0] += a4.x*w4.x; acc[0][1] += a4.x*w4.y; acc[0][2] += a4.x*w4.z; acc[0][3] += a4.x*w4.w; \
  acc[1][0] += a4.y*w4.x; acc[1][1] += a4.y*w4.y; acc[1][2] += a4.y*w4.z; acc[1][3] += a4.y*w4.w; \
  acc[2][0] += a4.z*w4.x; acc[2][1] += a4.z*w4.y; acc[2][2] += a4.z*w4.z; acc[2][3] += a4.z*w4.w; \
  acc[3][0] += a4.w*w4.x; acc[3][1] += a4.w*w4.y; acc[3][2] += a4.w*w4.z; acc[3][3] += a4.w*w4.w;

// ---------------- Tiled GEMM: C(bf16) = act(A(bf16)@W(fp32) + bias); TR: store C^T ----------------
// 64x64 tile, BK=16, 4x4/thread. blockIdx.z batching via gA/gW/gC element strides.
template <int ACT, int TR>
__global__ void __launch_bounds__(256) k_gemm(const bf16* __restrict__ A, int lda,
                                              const float* __restrict__ W, int ldw,
                                              const float* __restrict__ bias,
                                              bf16* __restrict__ C, int ldc, int K,
                                              int gA, int gW, int gC) {
  __shared__ float As[16][64];
  __shared__ float Ws[16][64];
  const int g = blockIdx.z;
  A += (size_t)g * gA; W += (size_t)g * gW; C += (size_t)g * gC;
  const int tx = threadIdx.x & 15, ty = threadIdx.x >> 4;
  const int bm = blockIdx.y * 64, bn = blockIdx.x * 64;
  const int lr = threadIdx.x >> 2;
  const int lc = (threadIdx.x & 3) * 4;
  const int wr = threadIdx.x >> 4;
  const int wc = (threadIdx.x & 15) * 4;
  float acc[4][4] = {};
  for (int k0 = 0; k0 < K; k0 += 16) {
    ushort4 av = *(const ushort4*)(A + (size_t)(bm + lr) * lda + k0 + lc);
    As[lc + 0][lr] = bits2f(av.x); As[lc + 1][lr] = bits2f(av.y);
    As[lc + 2][lr] = bits2f(av.z); As[lc + 3][lr] = bits2f(av.w);
    float4 wv = *(const float4*)(W + (size_t)(k0 + wr) * ldw + bn + wc);
    Ws[wr][wc + 0] = wv.x; Ws[wr][wc + 1] = wv.y; Ws[wr][wc + 2] = wv.z; Ws[wr][wc + 3] = wv.w;
    __syncthreads();
#pragma unroll
    for (int kk = 0; kk < 16; kk++) {
      float4 a4 = *(const float4*)&As[kk][ty * 4];
      float4 w4 = *(const float4*)&Ws[kk][tx * 4];
      FMA16
    }
    __syncthreads();
  }
#pragma unroll
  for (int i = 0; i < 4; i++) {
    int row = bm + ty * 4 + i;
#pragma unroll
    for (int j = 0; j < 4; j++) {
      int col = bn + tx * 4 + j;
      float v = acc[i][j];
      if (bias) v += bias[col];
      if (ACT == 1) v = v / (1.f + expf(-v));  // silu
      if (TR) C[(size_t)col * 4096 + row] = f2b(v);   // transposed store (for VT)
      else    C[(size_t)row * ldc + col] = f2b(v);
    }
  }
}

// ---------------- conv weight transpose: WC[kk][i][o] = conv_w[o][i][kk] (fp32 -> bf16) ----------------
__global__ void __launch_bounds__(256) k_convw(const float* __restrict__ cw, bf16* __restrict__ wc) {
  int idx = blockIdx.x * 256 + threadIdx.x;   // enumerates (o,i,kk) in input order
  int kk = idx & 3;
  int i  = (idx >> 2) & 1023;
  int o  = idx >> 12;
  wc[((size_t)kk << 20) + ((size_t)i << 10) + o] = f2b(cw[idx]);
}

// ---------------- causal conv1d as 4 shifted GEMMs, fused silu ----------------
__global__ void __launch_bounds__(256) k_conv(const bf16* __restrict__ a,
                                              const bf16* __restrict__ wcw,
                                              const float* __restrict__ cb,
                                              bf16* __restrict__ qk) {
  __shared__ float As[16][64];
  __shared__ float Ws[16][64];
  const int tx = threadIdx.x & 15, ty = threadIdx.x >> 4;
  const int bm = blockIdx.y * 64, bn = blockIdx.x * 64;
  const int lr = threadIdx.x >> 2;
  const int lc = (threadIdx.x & 3) * 4;
  const int wr = threadIdx.x >> 4;
  const int wc = (threadIdx.x & 15) * 4;
  const int m = bm + lr;
  const int b_ = m >> 11, t = m & 2047;
  float acc[4][4] = {};
  for (int kk = 0; kk < 4; kk++) {
    const int ts = t - 3 + kk;
    const bf16* arow = a + ((size_t)(b_ << 11) + ts) * DIM2X;
    const bf16* wbase = wcw + ((size_t)kk << 20);
    for (int k0 = 0; k0 < DIM2X; k0 += 16) {
      float a0 = 0.f, a1 = 0.f, a2 = 0.f, a3 = 0.f;
      if (ts >= 0) {
        ushort4 av = *(const ushort4*)(arow + k0 + lc);
        a0 = bits2f(av.x); a1 = bits2f(av.y); a2 = bits2f(av.z); a3 = bits2f(av.w);
      }
      As[lc + 0][lr] = a0; As[lc + 1][lr] = a1; As[lc + 2][lr] = a2; As[lc + 3][lr] = a3;
      ushort4 wv = *(const ushort4*)(wbase + (size_t)(k0 + wr) * DIM2X + bn + wc);
      Ws[wr][wc + 0] = bits2f(wv.x); Ws[wr][wc + 1] = bits2f(wv.y);
      Ws[wr][wc + 2] = bits2f(wv.z); Ws[wr][wc + 3] = bits2f(wv.w);
      __syncthreads();
#pragma unroll
      for (int kx = 0; kx < 16; kx++) {
        float4 a4 = *(const float4*)&As[kx][ty * 4];
        float4 w4 = *(const float4*)&Ws[kx][tx * 4];
        FMA16
      }
      __syncthreads();
    }
  }
#pragma unroll
  for (int i = 0; i < 4; i++) {
    int row = bm + ty * 4 + i;
#pragma unroll
    for (int j = 0; j < 4; j++) {
      int col = bn + tx * 4 + j;
      float v = acc[i][j] + cb[col];
      v = v / (1.f + expf(-v));  // silu
      qk[(size_t)row * DIM2X + col] = f2b(v);
    }
  }
}

// ---------------- gate GEMV: it = q@wi + wib ; ft = k@wf + wfb ([b,h,s] fp32 out) ----------------
__global__ void __launch_bounds__(256) k_gates(const bf16* __restrict__ q, const bf16* __restrict__ kk,
                                               const float* __restrict__ wi, const float* __restrict__ wib,
                                               const float* __restrict__ wf, const float* __restrict__ wfb,
                                               float* __restrict__ it, float* __restrict__ ft) {
  int gid  = blockIdx.x * 4 + (threadIdx.x >> 6);  // 0..8191 = which*4096 + m
  int lane = threadIdx.x & 63;
  int which = gid >> 12;
  int m = gid & 4095;
  const bf16* row = (which ? kk : q) + (size_t)m * DIM2X;
  const float* w = which ? wf : wi;
  float s[8] = {0, 0, 0, 0, 0, 0, 0, 0};
  for (int d = lane; d < DIM2X; d += 64) {
    float xv = b2f(row[d]);
    const float4* wp = (const float4*)(w + d * 8);
    float4 w0 = wp[0], w1 = wp[1];
    s[0] += xv * w0.x; s[1] += xv * w0.y; s[2] += xv * w0.z; s[3] += xv * w0.w;
    s[4] += xv * w1.x; s[5] += xv * w1.y; s[6] += xv * w1.z; s[7] += xv * w1.w;
  }
#pragma unroll
  for (int off = 32; off; off >>= 1) {
#pragma unroll
    for (int h = 0; h < 8; h++) s[h] += __shfl_xor(s[h], off);
  }
  if (lane == 0) {
    int b_ = m >> 11, tt = m & 2047;
    const float* wb = which ? wfb : wib;
    float* dst = which ? ft : it;
#pragma unroll
    for (int h = 0; h < 8; h++)
      dst[((size_t)(b_ * NHEADS + h)) * SEQ + tt] = s[h] + wb[h];
  }
}

// ---------------- per-(b,h) scan: cs = cumsum(logsigmoid(ft)); md = cs + prefmax(it - cs) ----------------
__global__ void __launch_bounds__(256) k_scan(const float* __restrict__ it, const float* __restrict__ ft,
                                              float* __restrict__ cs, float* __restrict__ md) {
  const int bh = blockIdx.x;
  const int t  = threadIdx.x;  // 256 threads, 8 elems each
  const float* fr = ft + (size_t)bh * SEQ;
  const float* ir = it + (size_t)bh * SEQ;
  float* csr = cs + (size_t)bh * SEQ;
  float* mdr = md + (size_t)bh * SEQ;
  __shared__ float tmp[256];
  float loc[8]; float run = 0.f;
#pragma unroll
  for (int j = 0; j < 8; j++) {
    float xv = fr[t * 8 + j];
    float ls = fminf(xv, 0.f) - log1pf(expf(-fabsf(xv)));  // stable log_sigmoid
    run += ls; loc[j] = run;
  }
  tmp[t] = run;
  __syncthreads();
  for (int off = 1; off < 256; off <<= 1) {
    float add = (t >= off) ? tmp[t - off] : 0.f;
    __syncthreads();
    tmp[t] += add;
    __syncthreads();
  }
  float exc = (t == 0) ? 0.f : tmp[t - 1];
  float csv[8];
#pragma unroll
  for (int j = 0; j < 8; j++) { csv[j] = loc[j] + exc; csr[t * 8 + j] = csv[j]; }
  __syncthreads();
  float rmax = -INFINITY; float gm[8];
#pragma unroll
  for (int j = 0; j < 8; j++) {
    float gv = ir[t * 8 + j] - csv[j];
    rmax = fmaxf(rmax, gv); gm[j] = rmax;
  }
  tmp[t] = rmax;
  __syncthreads();
  for (int off = 1; off < 256; off <<= 1) {
    float other = (t >= off) ? tmp[t - off] : -INFINITY;
    __syncthreads();
    tmp[t] = fmaxf(tmp[t], other);
    __syncthreads();
  }
  float emax = (t == 0) ? -INFINITY : tmp[t - 1];
#pragma unroll
  for (int j = 0; j < 8; j++) mdr[t * 8 + j] = csv[j] + fmaxf(gm[j], emax);
}

// ---------------- MFMA causal attention: 1 wave per 16-row i-tile ----------------
// QK^T: 4x mfma_16x16x32 over K=128 (Q in regs, K B-frags direct from global).
// Gate in C-layout; Sc -> LDS (bf16, padded) -> A-layout b128 reads; PV: 8x mfma
// per 32-wide j-pair with V B-frags direct from transposed VT (uint4 loads).
__global__ void __launch_bounds__(64) k_attn_mfma(const bf16* __restrict__ qh,
                                                  const bf16* __restrict__ kh,
                                                  const bf16* __restrict__ vt,
                                                  const float* __restrict__ cs,
                                                  const float* __restrict__ md,
                                                  const float* __restrict__ itl,
                                                  bf16* __restrict__ Hout) {
  const int bh = blockIdx.y, b_ = bh >> 3, h = bh & 7;
  const int it16 = 127 - blockIdx.x;          // heavy tiles dispatched first
  const int i0 = it16 * 16;
  const int lane = threadIdx.x & 63;
  const int col = lane & 15, quad = lane >> 4;
  __shared__ __align__(16) bf16 Sc[16][40];   // 16x32 + pad (80B row stride, 16B-aligned)

  const size_t baseQK = ((size_t)b_ * SEQ) * DIM2X + (size_t)h * HDIM;
  const float* csp = cs + (size_t)bh * SEQ;
  const float* mdp = md + (size_t)bh * SEQ;
  const float* itp = itl + (size_t)bh * SEQ;

  // Q A-fragments, K=128 in 4 chunks of 32: A[m=col][k=quad*8+j]
  short8 qf[4];
#pragma unroll
  for (int kc = 0; kc < 4; kc++)
    qf[kc] = *(const short8*)(qh + baseQK + (size_t)(i0 + col) * DIM2X + kc * 32 + quad * 8);

  float cs_i[4], md_i[4];
#pragma unroll
  for (int r = 0; r < 4; r++) {
    int i = i0 + quad * 4 + r;                // C-layout row
    cs_i[r] = csp[i]; md_i[r] = mdp[i];
  }

  f32x4 accpv[8];
#pragma unroll
  for (int nb = 0; nb < 8; nb++) accpv[nb] = (f32x4){0.f, 0.f, 0.f, 0.f};
  float rs[4] = {0.f, 0.f, 0.f, 0.f};

  const size_t vtb = (size_t)(h * HDIM) * 4096 + (size_t)b_ * SEQ;  // VT[d][b*2048+t]

  for (int j0p = 0; j0p <= i0; j0p += 32) {
    __syncthreads();                          // guard Sc vs previous iteration's reads
#pragma unroll
    for (int jt = 0; jt < 2; jt++) {
      const int j0 = j0p + jt * 16;
      float sv[4] = {0.f, 0.f, 0.f, 0.f};
      if (j0 <= i0) {
        f32x4 aq = (f32x4){0.f, 0.f, 0.f, 0.f};
#pragma unroll
        for (int kc = 0; kc < 4; kc++) {
          short8 bk = *(const short8*)(kh + baseQK + (size_t)(j0 + col) * DIM2X + kc * 32 + quad * 8);
          aq = __builtin_amdgcn_mfma_f32_16x16x32_bf16(qf[kc], bk, aq, 0, 0, 0);
        }
        const int j = j0 + col;
        const float gj = itp[j] - csp[j];
#pragma unroll
        for (int r = 0; r < 4; r++) {
          const int i = i0 + quad * 4 + r;
          float s = (j <= i) ? satexp(cs_i[r] + gj - md_i[r]) * aq[r] * (1.f / 32.f) : 0.f;
          sv[r] = s; rs[r] += s;
        }
      }
#pragma unroll
      for (int r = 0; r < 4; r++) Sc[quad * 4 + r][jt * 16 + col] = f2b(sv[r]);
    }
    __syncthreads();
    // Sc A-fragment: A[m=col][k=quad*8+j], K=32
    short8 af = *(const short8*)(&Sc[col][quad * 8]);
#pragma unroll
    for (int nb = 0; nb < 8; nb++) {
      short8 bv = *(const short8*)(vt + vtb + (size_t)(nb * 16 + col) * 4096 + j0p + quad * 8);
      accpv[nb] = __builtin_amdgcn_mfma_f32_16x16x32_bf16(af, bv, accpv[nb], 0, 0, 0);
    }
  }
  // row-sum reduction across the 16 lanes of each quad group
#pragma unroll
  for (int r = 0; r < 4; r++) {
    float v = rs[r];
    v += __shfl_xor(v, 1); v += __shfl_xor(v, 2);
    v += __shfl_xor(v, 4); v += __shfl_xor(v, 8);
    rs[r] = v;
  }
  float inv[4];
#pragma unroll
  for (int r = 0; r < 4; r++) {
    float maxit = fmaxf(fabsf(rs[r]), satexp(-md_i[r]));
    inv[r] = 1.f / (maxit + 1e-8f);
  }
#pragma unroll
  for (int nb = 0; nb < 8; nb++)
#pragma unroll
    for (int r = 0; r < 4; r++)
      Hout[baseQK + (size_t)(i0 + quad * 4 + r) * DIM2X + nb * 16 + col] = f2b(accpv[nb][r] * inv[r]);
}

// ---------------- GroupNorm(per-head over 128) + skip*qk then *bgate ----------------
__global__ void __launch_bounds__(256) k_gnorm(const bf16* __restrict__ H, const bf16* __restrict__ qk,
                                               const bf16* __restrict__ bg,
                                               const float* __restrict__ gw, const float* __restrict__ gb,
                                               const float* __restrict__ skip, bf16* __restrict__ pre) {
  int gid  = blockIdx.x * 4 + (threadIdx.x >> 6);  // (m,h)
  int lane = threadIdx.x & 63;
  int m = gid >> 3, h = gid & 7;
  const bf16* Hr = H + (size_t)m * DIM2X + (size_t)h * HDIM;
  float v0 = b2f(Hr[lane]), v1 = b2f(Hr[lane + 64]);
  float s = v0 + v1, sq = v0 * v0 + v1 * v1;
#pragma unroll
  for (int off = 32; off; off >>= 1) { s += __shfl_xor(s, off); sq += __shfl_xor(sq, off); }
  float mu  = s * (1.f / 128.f);
  float var = sq * (1.f / 128.f) - mu * mu;
  float rs  = rsqrtf(var + EPSF);
#pragma unroll
  for (int e = 0; e < 2; e++) {
    int c = lane + e * 64;
    int col = h * HDIM + c;
    float v = e ? v1 : v0;
    float hn = (v - mu) * rs * gw[col] + gb[col];
    size_t gidx = (size_t)m * DIM2X + col;
    pre[gidx] = f2b((hn + skip[col] * b2f(qk[gidx])) * b2f(bg[gidx]));
  }
}

// ---------------- final tiled GEMM: out(fp32) = x + pre@fin_w + fin_b ----------------
__global__ void __launch_bounds__(256) k_gemm_final(const bf16* __restrict__ A,
                                                    const float* __restrict__ W,
                                                    const float* __restrict__ bias,
                                                    const float* __restrict__ xres,
                                                    float* __restrict__ out) {
  __shared__ float As[16][64];
  __shared__ float Ws[16][64];
  const int tx = threadIdx.x & 15, ty = threadIdx.x >> 4;
  const int bm = blockIdx.y * 64, bn = blockIdx.x * 64;
  const int lr = threadIdx.x >> 2;
  const int lc = (threadIdx.x & 3) * 4;
  const int wr = threadIdx.x >> 4;
  const int wc = (threadIdx.x & 15) * 4;
  float acc[4][4] = {};
  for (int k0 = 0; k0 < DIM2X; k0 += 16) {
    ushort4 av = *(const ushort4*)(A + (size_t)(bm + lr) * DIM2X + k0 + lc);
    As[lc + 0][lr] = bits2f(av.x); As[lc + 1][lr] = bits2f(av.y);
    As[lc + 2][lr] = bits2f(av.z); As[lc + 3][lr] = bits2f(av.w);
    float4 wv = *(const float4*)(W + (size_t)(k0 + wr) * DIMX + bn + wc);
    Ws[wr][wc + 0] = wv.x; Ws[wr][wc + 1] = wv.y; Ws[wr][wc + 2] = wv.z; Ws[wr][wc + 3] = wv.w;
    __syncthreads();
#pragma unroll
    for (int kk = 0; kk < 16; kk++) {
      float4 a4 = *(const float4*)&As[kk][ty * 4];
      float4 w4 = *(const float4*)&Ws[kk][tx * 4];
      FMA16
    }
    __syncthreads();
  }
#pragma unroll
  for (int i = 0; i < 4; i++) {
    int row = bm + ty * 4 + i;
#pragma unroll
    for (int j = 0; j < 4; j++) {
      int col = bn + tx * 4 + j;
      size_t gidx = (size_t)row * DIMX + col;
      out[gidx] = acc[i][j] + bias[col] + xres[gidx];
    }
  }
}

extern "C" void kernel_launch(void* const* d_in, const int* in_sizes, int n_in,
                              void* d_out, int out_size, void* d_ws, size_t ws_size,
                              hipStream_t stream) {
  const float* x     = (const float*)d_in[0];
  const float* ln_w  = (const float*)d_in[1];
  const float* ln_b  = (const float*)d_in[2];
  const float* mlp1w = (const float*)d_in[3];
  const float* mlp1b = (const float*)d_in[4];
  const float* mlp2w = (const float*)d_in[5];
  const float* mlp2b = (const float*)d_in[6];
  const float* convw = (const float*)d_in[7];
  const float* convb = (const float*)d_in[8];
  const float* bqw   = (const float*)d_in[9];
  const float* bkw   = (const float*)d_in[10];
  const float* bvw   = (const float*)d_in[11];
  const float* wqw   = (const float*)d_in[12];
  const float* wqb   = (const float*)d_in[13];
  const float* wkw   = (const float*)d_in[14];
  const float* wkb   = (const float*)d_in[15];
  const float* wvw   = (const float*)d_in[16];
  const float* wvb   = (const float*)d_in[17];
  const float* wiw   = (const float*)d_in[18];
  const float* wib   = (const float*)d_in[19];
  const float* wfw   = (const float*)d_in[20];
  const float* wfb   = (const float*)d_in[21];
  const float* gnw   = (const float*)d_in[22];
  const float* gnb   = (const float*)d_in[23];
  const float* skip  = (const float*)d_in[24];
  const float* finw  = (const float*)d_in[25];
  const float* finb  = (const float*)d_in[26];
  float* out = (float*)d_out;   // fp32 output (verified round 8)

  // ---- workspace: gates first (512KB+), then 7 recycled 4M-elem bf16 slots (57MB) ----
  float* GA  = (float*)d_ws;
  float* ITb = GA;
  float* FTb = GA + 32768;
  float* CSb = GA + 65536;
  float* MDb = GA + 98304;
  const size_t SLOT = 4u * 1024u * 1024u;
  bf16* S0 = (bf16*)((char*)d_ws + (1 << 20));
  bf16* S1 = S0 + SLOT;
  bf16* S2 = S1 + SLOT;
  bf16* S3 = S2 + SLOT;
  bf16* S4 = S3 + SLOT;
  bf16* S5 = S4 + SLOT;
  bf16* S6 = S5 + SLOT;
  // liveness-checked recycling: WC shares LN slot (LN dead after mlp2);
  // QH=S0 (WC dead), KH=S1 (A_ dead), VT=S4 (Qb dead), Hb=S5 (Kb dead), PRE=S6 (Vb dead)
  bf16 *LN = S0, *A_ = S1, *BG = S2, *QKb = S3, *Qb = S4, *Kb = S5, *Vb = S6;
  bf16 *WC = S0, *QH = S0, *KH = S1, *VT = S4, *Hb = S5, *PRE = S6;

  k_layernorm<<<1024, 256, 0, stream>>>(x, ln_w, ln_b, LN);
  k_gemm<0,0><<<dim3(16, 64), 256, 0, stream>>>(LN, DIMX, mlp1w, DIM2X, mlp1b, A_, DIM2X, DIMX, 0, 0, 0);
  k_gemm<1,0><<<dim3(16, 64), 256, 0, stream>>>(LN, DIMX, mlp2w, DIM2X, mlp2b, BG, DIM2X, DIMX, 0, 0, 0);
  k_convw<<<16384, 256, 0, stream>>>(convw, WC);
  k_conv<<<dim3(16, 64), 256, 0, stream>>>(A_, WC, convb, QKb);
  // block-diagonal linears, batched over 4 groups via blockIdx.z
  k_gemm<0,0><<<dim3(4, 64, 4), 256, 0, stream>>>(QKb, DIM2X, bqw, 256, nullptr, Qb, DIM2X, 256, 256, 65536, 256);
  k_gemm<0,0><<<dim3(4, 64, 4), 256, 0, stream>>>(QKb, DIM2X, bkw, 256, nullptr, Kb, DIM2X, 256, 256, 65536, 256);
  k_gemm<0,0><<<dim3(4, 64, 4), 256, 0, stream>>>(A_,  DIM2X, bvw, 256, nullptr, Vb, DIM2X, 256, 256, 65536, 256);
  k_gates<<<2048, 256, 0, stream>>>(Qb, Kb, wiw, wib, wfw, wfb, ITb, FTb);
  k_scan<<<16, 256, 0, stream>>>(ITb, FTb, CSb, MDb);
  k_gemm<0,0><<<dim3(16, 64), 256, 0, stream>>>(Qb, DIM2X, wqw, DIM2X, wqb, QH, DIM2X, DIM2X, 0, 0, 0);
  k_gemm<0,0><<<dim3(16, 64), 256, 0, stream>>>(Kb, DIM2X, wkw, DIM2X, wkb, KH, DIM2X, DIM2X, 0, 0, 0);
  k_gemm<0,1><<<dim3(16, 64), 256, 0, stream>>>(Vb, DIM2X, wvw, DIM2X, wvb, VT, 0, DIM2X, 0, 0, 0);  // V^T
  k_attn_mfma<<<dim3(128, 16), 64, 0, stream>>>(QH, KH, VT, CSb, MDb, ITb, Hb);
  k_gnorm<<<8192, 256, 0, stream>>>(Hb, QKb, BG, gnw, gnb, skip, PRE);
  k_gemm_final<<<dim3(8, 64), 256, 0, stream>>>(PRE, finw, finb, x, out);
}

// Round 11
// 1061.876 us; speedup vs baseline: 36.0631x; 1.4825x over previous
//
#include <hip/hip_runtime.h>
#include <hip/hip_bf16.h>
#include <cmath>

typedef __hip_bfloat16 bf16;
typedef __attribute__((ext_vector_type(8))) short short8;   // 8 bf16 (4 VGPRs)
typedef __attribute__((ext_vector_type(4))) float f32x4;

#define SEQ   2048
#define DIMX  512
#define DIM2X 1024
#define NHEADS 8
#define HDIM  128
#define EPSF  1e-5f

__device__ __forceinline__ float b2f(bf16 v) { return __bfloat162float(v); }
__device__ __forceinline__ bf16 f2b(float f) { return __float2bfloat16(f); }
__device__ __forceinline__ unsigned short f2bu(float f) { bf16 t = __float2bfloat16(f); return *(unsigned short*)&t; }
__device__ __forceinline__ float satexp(float x) { return expf(fminf(x, 30.f)); }

// ---------------- LayerNorm: one wave per row of 512 (fp32 in, bf16 out) ----------------
__global__ void __launch_bounds__(256) k_layernorm(const float* __restrict__ x,
                                                   const float* __restrict__ w,
                                                   const float* __restrict__ b,
                                                   bf16* __restrict__ out) {
  int row  = blockIdx.x * 4 + (threadIdx.x >> 6);
  int lane = threadIdx.x & 63;
  const float* xr = x + (size_t)row * DIMX;
  float v[8]; float s = 0.f, sq = 0.f;
#pragma unroll
  for (int i = 0; i < 8; i++) {
    float f = xr[lane + i * 64];
    v[i] = f; s += f; sq += f * f;
  }
#pragma unroll
  for (int off = 32; off; off >>= 1) { s += __shfl_xor(s, off); sq += __shfl_xor(sq, off); }
  float mu  = s * (1.f / DIMX);
  float var = sq * (1.f / DIMX) - mu * mu;
  float rs  = rsqrtf(var + EPSF);
  bf16* o = out + (size_t)row * DIMX;
#pragma unroll
  for (int i = 0; i < 8; i++) {
    int c = lane + i * 64;
    o[c] = f2b((v[i] - mu) * rs * w[c] + b[c]);
  }
}

// ---------------- weight cast+transpose: WT[n][k] = bf16(W[k][n]), LDS-tiled ----------------
__global__ void __launch_bounds__(256) k_castT(const float* __restrict__ W, bf16* __restrict__ WT,
                                               int K, int N, int gW, int gT) {
  __shared__ float t[32][33];
  W  += (size_t)blockIdx.z * gW;
  WT += (size_t)blockIdx.z * gT;
  const int k0 = blockIdx.y * 32, n0 = blockIdx.x * 32;
  const int r = threadIdx.x >> 5, c = threadIdx.x & 31;
#pragma unroll
  for (int i = 0; i < 4; i++)
    t[r + i * 8][c] = W[(size_t)(k0 + r + i * 8) * N + n0 + c];
  __syncthreads();
#pragma unroll
  for (int i = 0; i < 4; i++)
    WT[(size_t)(n0 + r + i * 8) * K + k0 + c] = f2b(t[c][r + i * 8]);
}

// ---------------- conv weight reshape: WcT[kk][o][i] = bf16(conv_w[o][i][kk]) ----------------
__global__ void __launch_bounds__(256) k_convwT(const float* __restrict__ cw, bf16* __restrict__ wc) {
  int idx = blockIdx.x * 256 + threadIdx.x;     // output-ordered (kk,o,i)
  int kk = idx >> 20, o = (idx >> 10) & 1023, i = idx & 1023;
  wc[idx] = f2b(cw[(size_t)o * 4096 + i * 4 + kk]);
}

// ---------------- MFMA GEMM: 64x64 block (2x2 waves, 32x32/wave), K-step 32, no LDS ----------------
// A bf16 [M,K] lda; WT bf16 [N,K]; STORE: 0=bf16 C, 1=bf16 transposed (VT[n*4096+m]), 2=fp32+residual.
template <int ACT, int STORE>
__global__ void __launch_bounds__(256) k_mgemm(const bf16* __restrict__ A, int lda,
                                               const bf16* __restrict__ WT,
                                               const float* __restrict__ bias,
                                               void* __restrict__ Cv,
                                               const float* __restrict__ xres,
                                               int ldc, int K,
                                               int gA, int gW, int gC) {
  const int g = blockIdx.z;
  A  += (size_t)g * gA;
  WT += (size_t)g * gW;
  const int lane = threadIdx.x & 63;
  const int w = threadIdx.x >> 6, wy = w >> 1, wx = w & 1;
  const int col = lane & 15, quad = lane >> 4;
  const int bm = blockIdx.y * 64, bn = blockIdx.x * 64;
  f32x4 acc[2][2];
#pragma unroll
  for (int a = 0; a < 2; a++)
#pragma unroll
    for (int b = 0; b < 2; b++) acc[a][b] = (f32x4){0.f, 0.f, 0.f, 0.f};
  const bf16* Ap = A + (size_t)(bm + wy * 32 + col) * lda + quad * 8;
  const bf16* Bp = WT + (size_t)(bn + wx * 32 + col) * K + quad * 8;
  for (int k0 = 0; k0 < K; k0 += 32) {
    short8 a0 = *(const short8*)(Ap + k0);
    short8 a1 = *(const short8*)(Ap + (size_t)16 * lda + k0);
    short8 b0 = *(const short8*)(Bp + k0);
    short8 b1 = *(const short8*)(Bp + (size_t)16 * K + k0);
    acc[0][0] = __builtin_amdgcn_mfma_f32_16x16x32_bf16(a0, b0, acc[0][0], 0, 0, 0);
    acc[0][1] = __builtin_amdgcn_mfma_f32_16x16x32_bf16(a0, b1, acc[0][1], 0, 0, 0);
    acc[1][0] = __builtin_amdgcn_mfma_f32_16x16x32_bf16(a1, b0, acc[1][0], 0, 0, 0);
    acc[1][1] = __builtin_amdgcn_mfma_f32_16x16x32_bf16(a1, b1, acc[1][1], 0, 0, 0);
  }
#pragma unroll
  for (int mt = 0; mt < 2; mt++) {
#pragma unroll
    for (int nt = 0; nt < 2; nt++) {
      const int n = bn + wx * 32 + nt * 16 + col;
      const int mrow0 = bm + wy * 32 + mt * 16 + quad * 4;
      float bs = bias ? bias[n] : 0.f;
      if (STORE == 1) {
        // transposed bf16 store: pack 4 consecutive rows into one 8B store at VT[n*4096 + mrow0]
        bf16* C = (bf16*)Cv + (size_t)g * gC;
        ushort4 pk;
        pk.x = f2bu(acc[mt][nt][0] + bs); pk.y = f2bu(acc[mt][nt][1] + bs);
        pk.z = f2bu(acc[mt][nt][2] + bs); pk.w = f2bu(acc[mt][nt][3] + bs);
        *(ushort4*)(C + (size_t)n * 4096 + mrow0) = pk;
      } else if (STORE == 2) {
        float* O = (float*)Cv + (size_t)g * gC;
#pragma unroll
        for (int r = 0; r < 4; r++) {
          size_t gi = (size_t)(mrow0 + r) * ldc + n;
          O[gi] = acc[mt][nt][r] + bs + xres[gi];
        }
      } else {
        bf16* C = (bf16*)Cv + (size_t)g * gC;
#pragma unroll
        for (int r = 0; r < 4; r++) {
          float v = acc[mt][nt][r] + bs;
          if (ACT == 1) v = v / (1.f + expf(-v));  // silu
          C[(size_t)(mrow0 + r) * ldc + n] = f2b(v);
        }
      }
    }
  }
}

// ---------------- MFMA causal conv1d: 4 shifted K-passes, fused bias+silu ----------------
__global__ void __launch_bounds__(256) k_conv_mfma(const bf16* __restrict__ a,
                                                   const bf16* __restrict__ wct,
                                                   const float* __restrict__ cb,
                                                   bf16* __restrict__ qk) {
  const int lane = threadIdx.x & 63;
  const int w = threadIdx.x >> 6, wy = w >> 1, wx = w & 1;
  const int col = lane & 15, quad = lane >> 4;
  const int bm = blockIdx.y * 64, bn = blockIdx.x * 64;
  const int b_ = bm >> 11;                      // batch uniform within 64-row tile
  const int t0 = (bm & 2047) + wy * 32 + col;   // row-in-sequence for mt=0 A-frag
  f32x4 acc[2][2];
#pragma unroll
  for (int x = 0; x < 2; x++)
#pragma unroll
    for (int y = 0; y < 2; y++) acc[x][y] = (f32x4){0.f, 0.f, 0.f, 0.f};
  const bf16* Bp = wct + (size_t)(bn + wx * 32 + col) * 1024 + quad * 8;
  for (int kk = 0; kk < 4; kk++) {
    const int ts0 = t0 - 3 + kk;                // may be <0 (first 3 rows only)
    const int ts1 = ts0 + 16;                   // always >= 13
    const bf16* ap0 = a + ((size_t)(b_ << 11) + ts0) * DIM2X + quad * 8;
    const bf16* ap1 = a + ((size_t)(b_ << 11) + ts1) * DIM2X + quad * 8;
    const bf16* bp = Bp + (size_t)kk * 1048576;
    for (int k0 = 0; k0 < DIM2X; k0 += 32) {
      short8 a0 = {0, 0, 0, 0, 0, 0, 0, 0};
      if (ts0 >= 0) a0 = *(const short8*)(ap0 + k0);
      short8 a1 = *(const short8*)(ap1 + k0);
      short8 b0 = *(const short8*)(bp + k0);
      short8 b1 = *(const short8*)(bp + (size_t)16 * 1024 + k0);
      acc[0][0] = __builtin_amdgcn_mfma_f32_16x16x32_bf16(a0, b0, acc[0][0], 0, 0, 0);
      acc[0][1] = __builtin_amdgcn_mfma_f32_16x16x32_bf16(a0, b1, acc[0][1], 0, 0, 0);
      acc[1][0] = __builtin_amdgcn_mfma_f32_16x16x32_bf16(a1, b0, acc[1][0], 0, 0, 0);
      acc[1][1] = __builtin_amdgcn_mfma_f32_16x16x32_bf16(a1, b1, acc[1][1], 0, 0, 0);
    }
  }
#pragma unroll
  for (int mt = 0; mt < 2; mt++) {
#pragma unroll
    for (int nt = 0; nt < 2; nt++) {
      const int n = bn + wx * 32 + nt * 16 + col;
      const int mrow0 = bm + wy * 32 + mt * 16 + quad * 4;
      const float bs = cb[n];
#pragma unroll
      for (int r = 0; r < 4; r++) {
        float v = acc[mt][nt][r] + bs;
        v = v / (1.f + expf(-v));  // silu
        qk[(size_t)(mrow0 + r) * DIM2X + n] = f2b(v);
      }
    }
  }
}

// ---------------- gate GEMV: it = q@wi + wib ; ft = k@wf + wfb ([b,h,s] fp32 out) ----------------
__global__ void __launch_bounds__(256) k_gates(const bf16* __restrict__ q, const bf16* __restrict__ kk,
                                               const float* __restrict__ wi, const float* __restrict__ wib,
                                               const float* __restrict__ wf, const float* __restrict__ wfb,
                                               float* __restrict__ it, float* __restrict__ ft) {
  int gid  = blockIdx.x * 4 + (threadIdx.x >> 6);  // 0..8191 = which*4096 + m
  int lane = threadIdx.x & 63;
  int which = gid >> 12;
  int m = gid & 4095;
  const bf16* row = (which ? kk : q) + (size_t)m * DIM2X;
  const float* w = which ? wf : wi;
  float s[8] = {0, 0, 0, 0, 0, 0, 0, 0};
  for (int d = lane; d < DIM2X; d += 64) {
    float xv = b2f(row[d]);
    const float4* wp = (const float4*)(w + d * 8);
    float4 w0 = wp[0], w1 = wp[1];
    s[0] += xv * w0.x; s[1] += xv * w0.y; s[2] += xv * w0.z; s[3] += xv * w0.w;
    s[4] += xv * w1.x; s[5] += xv * w1.y; s[6] += xv * w1.z; s[7] += xv * w1.w;
  }
#pragma unroll
  for (int off = 32; off; off >>= 1) {
#pragma unroll
    for (int h = 0; h < 8; h++) s[h] += __shfl_xor(s[h], off);
  }
  if (lane == 0) {
    int b_ = m >> 11, tt = m & 2047;
    const float* wb = which ? wfb : wib;
    float* dst = which ? ft : it;
#pragma unroll
    for (int h = 0; h < 8; h++)
      dst[((size_t)(b_ * NHEADS + h)) * SEQ + tt] = s[h] + wb[h];
  }
}

// ---------------- per-(b,h) scan: cs = cumsum(logsigmoid(ft)); md = cs + prefmax(it - cs) ----------------
__global__ void __launch_bounds__(256) k_scan(const float* __restrict__ it, const float* __restrict__ ft,
                                              float* __restrict__ cs, float* __restrict__ md) {
  const int bh = blockIdx.x;
  const int t  = threadIdx.x;  // 256 threads, 8 elems each
  const float* fr = ft + (size_t)bh * SEQ;
  const float* ir = it + (size_t)bh * SEQ;
  float* csr = cs + (size_t)bh * SEQ;
  float* mdr = md + (size_t)bh * SEQ;
  __shared__ float tmp[256];
  float loc[8]; float run = 0.f;
#pragma unroll
  for (int j = 0; j < 8; j++) {
    float xv = fr[t * 8 + j];
    float ls = fminf(xv, 0.f) - log1pf(expf(-fabsf(xv)));  // stable log_sigmoid
    run += ls; loc[j] = run;
  }
  tmp[t] = run;
  __syncthreads();
  for (int off = 1; off < 256; off <<= 1) {
    float add = (t >= off) ? tmp[t - off] : 0.f;
    __syncthreads();
    tmp[t] += add;
    __syncthreads();
  }
  float exc = (t == 0) ? 0.f : tmp[t - 1];
  float csv[8];
#pragma unroll
  for (int j = 0; j < 8; j++) { csv[j] = loc[j] + exc; csr[t * 8 + j] = csv[j]; }
  __syncthreads();
  float rmax = -INFINITY; float gm[8];
#pragma unroll
  for (int j = 0; j < 8; j++) {
    float gv = ir[t * 8 + j] - csv[j];
    rmax = fmaxf(rmax, gv); gm[j] = rmax;
  }
  tmp[t] = rmax;
  __syncthreads();
  for (int off = 1; off < 256; off <<= 1) {
    float other = (t >= off) ? tmp[t - off] : -INFINITY;
    __syncthreads();
    tmp[t] = fmaxf(tmp[t], other);
    __syncthreads();
  }
  float emax = (t == 0) ? -INFINITY : tmp[t - 1];
#pragma unroll
  for (int j = 0; j < 8; j++) mdr[t * 8 + j] = csv[j] + fmaxf(gm[j], emax);
}

// ---------------- MFMA causal attention: 1 wave per 16-row i-tile (validated round 10) ----------------
__global__ void __launch_bounds__(64) k_attn_mfma(const bf16* __restrict__ qh,
                                                  const bf16* __restrict__ kh,
                                                  const bf16* __restrict__ vt,
                                                  const float* __restrict__ cs,
                                                  const float* __restrict__ md,
                                                  const float* __restrict__ itl,
                                                  bf16* __restrict__ Hout) {
  const int bh = blockIdx.y, b_ = bh >> 3, h = bh & 7;
  const int it16 = 127 - blockIdx.x;          // heavy tiles dispatched first
  const int i0 = it16 * 16;
  const int lane = threadIdx.x & 63;
  const int col = lane & 15, quad = lane >> 4;
  __shared__ __align__(16) bf16 Sc[16][40];

  const size_t baseQK = ((size_t)b_ * SEQ) * DIM2X + (size_t)h * HDIM;
  const float* csp = cs + (size_t)bh * SEQ;
  const float* mdp = md + (size_t)bh * SEQ;
  const float* itp = itl + (size_t)bh * SEQ;

  short8 qf[4];
#pragma unroll
  for (int kc = 0; kc < 4; kc++)
    qf[kc] = *(const short8*)(qh + baseQK + (size_t)(i0 + col) * DIM2X + kc * 32 + quad * 8);

  float cs_i[4], md_i[4];
#pragma unroll
  for (int r = 0; r < 4; r++) {
    int i = i0 + quad * 4 + r;
    cs_i[r] = csp[i]; md_i[r] = mdp[i];
  }

  f32x4 accpv[8];
#pragma unroll
  for (int nb = 0; nb < 8; nb++) accpv[nb] = (f32x4){0.f, 0.f, 0.f, 0.f};
  float rs[4] = {0.f, 0.f, 0.f, 0.f};

  const size_t vtb = (size_t)(h * HDIM) * 4096 + (size_t)b_ * SEQ;

  for (int j0p = 0; j0p <= i0; j0p += 32) {
    __syncthreads();
#pragma unroll
    for (int jt = 0; jt < 2; jt++) {
      const int j0 = j0p + jt * 16;
      float sv[4] = {0.f, 0.f, 0.f, 0.f};
      if (j0 <= i0) {
        f32x4 aq = (f32x4){0.f, 0.f, 0.f, 0.f};
#pragma unroll
        for (int kc = 0; kc < 4; kc++) {
          short8 bk = *(const short8*)(kh + baseQK + (size_t)(j0 + col) * DIM2X + kc * 32 + quad * 8);
          aq = __builtin_amdgcn_mfma_f32_16x16x32_bf16(qf[kc], bk, aq, 0, 0, 0);
        }
        const int j = j0 + col;
        const float gj = itp[j] - csp[j];
#pragma unroll
        for (int r = 0; r < 4; r++) {
          const int i = i0 + quad * 4 + r;
          float s = (j <= i) ? satexp(cs_i[r] + gj - md_i[r]) * aq[r] * (1.f / 32.f) : 0.f;
          sv[r] = s; rs[r] += s;
        }
      }
#pragma unroll
      for (int r = 0; r < 4; r++) Sc[quad * 4 + r][jt * 16 + col] = f2b(sv[r]);
    }
    __syncthreads();
    short8 af = *(const short8*)(&Sc[col][quad * 8]);
#pragma unroll
    for (int nb = 0; nb < 8; nb++) {
      short8 bv = *(const short8*)(vt + vtb + (size_t)(nb * 16 + col) * 4096 + j0p + quad * 8);
      accpv[nb] = __builtin_amdgcn_mfma_f32_16x16x32_bf16(af, bv, accpv[nb], 0, 0, 0);
    }
  }
#pragma unroll
  for (int r = 0; r < 4; r++) {
    float v = rs[r];
    v += __shfl_xor(v, 1); v += __shfl_xor(v, 2);
    v += __shfl_xor(v, 4); v += __shfl_xor(v, 8);
    rs[r] = v;
  }
  float inv[4];
#pragma unroll
  for (int r = 0; r < 4; r++) {
    float maxit = fmaxf(fabsf(rs[r]), satexp(-md_i[r]));
    inv[r] = 1.f / (maxit + 1e-8f);
  }
#pragma unroll
  for (int nb = 0; nb < 8; nb++)
#pragma unroll
    for (int r = 0; r < 4; r++)
      Hout[baseQK + (size_t)(i0 + quad * 4 + r) * DIM2X + nb * 16 + col] = f2b(accpv[nb][r] * inv[r]);
}

// ---------------- GroupNorm(per-head over 128) + skip*qk then *bgate ----------------
__global__ void __launch_bounds__(256) k_gnorm(const bf16* __restrict__ H, const bf16* __restrict__ qk,
                                               const bf16* __restrict__ bg,
                                               const float* __restrict__ gw, const float* __restrict__ gb,
                                               const float* __restrict__ skip, bf16* __restrict__ pre) {
  int gid  = blockIdx.x * 4 + (threadIdx.x >> 6);  // (m,h)
  int lane = threadIdx.x & 63;
  int m = gid >> 3, h = gid & 7;
  const bf16* Hr = H + (size_t)m * DIM2X + (size_t)h * HDIM;
  float v0 = b2f(Hr[lane]), v1 = b2f(Hr[lane + 64]);
  float s = v0 + v1, sq = v0 * v0 + v1 * v1;
#pragma unroll
  for (int off = 32; off; off >>= 1) { s += __shfl_xor(s, off); sq += __shfl_xor(sq, off); }
  float mu  = s * (1.f / 128.f);
  float var = sq * (1.f / 128.f) - mu * mu;
  float rs  = rsqrtf(var + EPSF);
#pragma unroll
  for (int e = 0; e < 2; e++) {
    int c = lane + e * 64;
    int col = h * HDIM + c;
    float v = e ? v1 : v0;
    float hn = (v - mu) * rs * gw[col] + gb[col];
    size_t gidx = (size_t)m * DIM2X + col;
    pre[gidx] = f2b((hn + skip[col] * b2f(qk[gidx])) * b2f(bg[gidx]));
  }
}

extern "C" void kernel_launch(void* const* d_in, const int* in_sizes, int n_in,
                              void* d_out, int out_size, void* d_ws, size_t ws_size,
                              hipStream_t stream) {
  const float* x     = (const float*)d_in[0];
  const float* ln_w  = (const float*)d_in[1];
  const float* ln_b  = (const float*)d_in[2];
  const float* mlp1w = (const float*)d_in[3];
  const float* mlp1b = (const float*)d_in[4];
  const float* mlp2w = (const float*)d_in[5];
  const float* mlp2b = (const float*)d_in[6];
  const float* convw = (const float*)d_in[7];
  const float* convb = (const float*)d_in[8];
  const float* bqw   = (const float*)d_in[9];
  const float* bkw   = (const float*)d_in[10];
  const float* bvw   = (const float*)d_in[11];
  const float* wqw   = (const float*)d_in[12];
  const float* wqb   = (const float*)d_in[13];
  const float* wkw   = (const float*)d_in[14];
  const float* wkb   = (const float*)d_in[15];
  const float* wvw   = (const float*)d_in[16];
  const float* wvb   = (const float*)d_in[17];
  const float* wiw   = (const float*)d_in[18];
  const float* wib   = (const float*)d_in[19];
  const float* wfw   = (const float*)d_in[20];
  const float* wfb   = (const float*)d_in[21];
  const float* gnw   = (const float*)d_in[22];
  const float* gnb   = (const float*)d_in[23];
  const float* skip  = (const float*)d_in[24];
  const float* finw  = (const float*)d_in[25];
  const float* finb  = (const float*)d_in[26];
  float* out = (float*)d_out;   // fp32 output (verified round 8)

  // ---- ws: gates (1MB hdr) | 7 recycled 8MB bf16 slots | bf16 WT region (18.5MB) = 75.5MB ----
  float* GA  = (float*)d_ws;
  float* ITb = GA;
  float* FTb = GA + 32768;
  float* CSb = GA + 65536;
  float* MDb = GA + 98304;
  const size_t SLOT = 4u * 1024u * 1024u;
  bf16* S0 = (bf16*)((char*)d_ws + (1 << 20));
  bf16* S1 = S0 + SLOT;
  bf16* S2 = S1 + SLOT;
  bf16* S3 = S2 + SLOT;
  bf16* S4 = S3 + SLOT;
  bf16* S5 = S4 + SLOT;
  bf16* S6 = S5 + SLOT;
  bf16 *LN = S0, *A_ = S1, *BG = S2, *QKb = S3, *Qb = S4, *Kb = S5, *Vb = S6;
  bf16 *QH = S0, *KH = S1, *VT = S4, *Hb = S5, *PRE = S6;  // liveness-checked recycling
  // transposed bf16 weights (persistent through launch)
  bf16* WTb   = S6 + SLOT;
  bf16* mlp1T = WTb;                 // 512K
  bf16* mlp2T = WTb + 524288;        // 512K
  bf16* convT = WTb + 1048576;       // 4M
  bf16* bqT   = WTb + 5242880;       // 256K
  bf16* bkT   = bqT + 262144;
  bf16* bvT   = bkT + 262144;
  bf16* wqT   = bvT + 262144;        // 1M each
  bf16* wkT   = wqT + 1048576;
  bf16* wvT   = wkT + 1048576;
  bf16* finT  = wvT + 1048576;       // 512K -> total 9.25M elems

  // weight preprocessing (independent, cheap)
  k_castT<<<dim3(32, 16), 256, 0, stream>>>(mlp1w, mlp1T, DIMX, DIM2X, 0, 0);
  k_castT<<<dim3(32, 16), 256, 0, stream>>>(mlp2w, mlp2T, DIMX, DIM2X, 0, 0);
  k_convwT<<<16384, 256, 0, stream>>>(convw, convT);
  k_castT<<<dim3(8, 8, 4), 256, 0, stream>>>(bqw, bqT, 256, 256, 65536, 65536);
  k_castT<<<dim3(8, 8, 4), 256, 0, stream>>>(bkw, bkT, 256, 256, 65536, 65536);
  k_castT<<<dim3(8, 8, 4), 256, 0, stream>>>(bvw, bvT, 256, 256, 65536, 65536);
  k_castT<<<dim3(32, 32), 256, 0, stream>>>(wqw, wqT, DIM2X, DIM2X, 0, 0);
  k_castT<<<dim3(32, 32), 256, 0, stream>>>(wkw, wkT, DIM2X, DIM2X, 0, 0);
  k_castT<<<dim3(32, 32), 256, 0, stream>>>(wvw, wvT, DIM2X, DIM2X, 0, 0);
  k_castT<<<dim3(16, 32), 256, 0, stream>>>(finw, finT, DIM2X, DIMX, 0, 0);

  k_layernorm<<<1024, 256, 0, stream>>>(x, ln_w, ln_b, LN);
  k_mgemm<0,0><<<dim3(16, 64), 256, 0, stream>>>(LN, DIMX, mlp1T, mlp1b, A_, nullptr, DIM2X, DIMX, 0, 0, 0);
  k_mgemm<1,0><<<dim3(16, 64), 256, 0, stream>>>(LN, DIMX, mlp2T, mlp2b, BG, nullptr, DIM2X, DIMX, 0, 0, 0);
  k_conv_mfma<<<dim3(16, 64), 256, 0, stream>>>(A_, convT, convb, QKb);
  // block-diagonal linears (z over 4 groups)
  k_mgemm<0,0><<<dim3(4, 64, 4), 256, 0, stream>>>(QKb, DIM2X, bqT, nullptr, Qb, nullptr, DIM2X, 256, 256, 65536, 256);
  k_mgemm<0,0><<<dim3(4, 64, 4), 256, 0, stream>>>(QKb, DIM2X, bkT, nullptr, Kb, nullptr, DIM2X, 256, 256, 65536, 256);
  k_mgemm<0,0><<<dim3(4, 64, 4), 256, 0, stream>>>(A_,  DIM2X, bvT, nullptr, Vb, nullptr, DIM2X, 256, 256, 65536, 256);
  k_gates<<<2048, 256, 0, stream>>>(Qb, Kb, wiw, wib, wfw, wfb, ITb, FTb);
  k_scan<<<16, 256, 0, stream>>>(ITb, FTb, CSb, MDb);
  k_mgemm<0,0><<<dim3(16, 64), 256, 0, stream>>>(Qb, DIM2X, wqT, wqb, QH, nullptr, DIM2X, DIM2X, 0, 0, 0);
  k_mgemm<0,0><<<dim3(16, 64), 256, 0, stream>>>(Kb, DIM2X, wkT, wkb, KH, nullptr, DIM2X, DIM2X, 0, 0, 0);
  k_mgemm<0,1><<<dim3(16, 64), 256, 0, stream>>>(Vb, DIM2X, wvT, wvb, VT, nullptr, 0, DIM2X, 0, 0, 0);  // V^T
  k_attn_mfma<<<dim3(128, 16), 64, 0, stream>>>(QH, KH, VT, CSb, MDb, ITb, Hb);
  k_gnorm<<<8192, 256, 0, stream>>>(Hb, QKb, BG, gnw, gnb, skip, PRE);
  k_mgemm<0,2><<<dim3(8, 64), 256, 0, stream>>>(PRE, DIM2X, finT, finb, out, x, DIMX, DIM2X, 0, 0, 0);
}

// Round 12
// 922.728 us; speedup vs baseline: 41.5014x; 1.1508x over previous
//
#include <hip/hip_runtime.h>
#include <hip/hip_bf16.h>
#include <cmath>

typedef __hip_bfloat16 bf16;
typedef __attribute__((ext_vector_type(8))) short short8;   // 8 bf16 (4 VGPRs)
typedef __attribute__((ext_vector_type(4))) float f32x4;

#define SEQ   2048
#define DIMX  512
#define DIM2X 1024
#define NHEADS 8
#define HDIM  128
#define EPSF  1e-5f

__device__ __forceinline__ float b2f(bf16 v) { return __bfloat162float(v); }
__device__ __forceinline__ bf16 f2b(float f) { return __float2bfloat16(f); }
__device__ __forceinline__ unsigned short f2bu(float f) { bf16 t = __float2bfloat16(f); return *(unsigned short*)&t; }
__device__ __forceinline__ float satexp(float x) { return expf(fminf(x, 30.f)); }

// ---------------- LayerNorm: one wave per row of 512 (fp32 in, bf16 out) ----------------
__global__ void __launch_bounds__(256) k_layernorm(const float* __restrict__ x,
                                                   const float* __restrict__ w,
                                                   const float* __restrict__ b,
                                                   bf16* __restrict__ out) {
  int row  = blockIdx.x * 4 + (threadIdx.x >> 6);
  int lane = threadIdx.x & 63;
  const float* xr = x + (size_t)row * DIMX;
  float v[8]; float s = 0.f, sq = 0.f;
#pragma unroll
  for (int i = 0; i < 8; i++) {
    float f = xr[lane + i * 64];
    v[i] = f; s += f; sq += f * f;
  }
#pragma unroll
  for (int off = 32; off; off >>= 1) { s += __shfl_xor(s, off); sq += __shfl_xor(sq, off); }
  float mu  = s * (1.f / DIMX);
  float var = sq * (1.f / DIMX) - mu * mu;
  float rs  = rsqrtf(var + EPSF);
  bf16* o = out + (size_t)row * DIMX;
#pragma unroll
  for (int i = 0; i < 8; i++) {
    int c = lane + i * 64;
    o[c] = f2b((v[i] - mu) * rs * w[c] + b[c]);
  }
}

// ---------------- weight cast+transpose: WT[n][k] = bf16(W[k][n]), LDS-tiled ----------------
__global__ void __launch_bounds__(256) k_castT(const float* __restrict__ W, bf16* __restrict__ WT,
                                               int K, int N, int gW, int gT) {
  __shared__ float t[32][33];
  W  += (size_t)blockIdx.z * gW;
  WT += (size_t)blockIdx.z * gT;
  const int k0 = blockIdx.y * 32, n0 = blockIdx.x * 32;
  const int r = threadIdx.x >> 5, c = threadIdx.x & 31;
#pragma unroll
  for (int i = 0; i < 4; i++)
    t[r + i * 8][c] = W[(size_t)(k0 + r + i * 8) * N + n0 + c];
  __syncthreads();
#pragma unroll
  for (int i = 0; i < 4; i++)
    WT[(size_t)(n0 + r + i * 8) * K + k0 + c] = f2b(t[c][r + i * 8]);
}

// ---------------- conv weight reshape: WcT[kk][o][i] = bf16(conv_w[o][i][kk]) ----------------
__global__ void __launch_bounds__(256) k_convwT(const float* __restrict__ cw, bf16* __restrict__ wc) {
  int idx = blockIdx.x * 256 + threadIdx.x;     // output-ordered (kk,o,i)
  int kk = idx >> 20, o = (idx >> 10) & 1023, i = idx & 1023;
  wc[idx] = f2b(cw[(size_t)o * 4096 + i * 4 + kk]);
}

// ---------------- MFMA GEMM: 64x64 block (2x2 waves, 32x32/wave), K-step 32, no LDS ----------------
// A bf16 [M,K] lda; WT bf16 [N,K]; STORE: 0=bf16 C, 1=bf16 transposed (VT[n*4096+m]), 2=fp32+residual.
template <int ACT, int STORE>
__global__ void __launch_bounds__(256) k_mgemm(const bf16* __restrict__ A, int lda,
                                               const bf16* __restrict__ WT,
                                               const float* __restrict__ bias,
                                               void* __restrict__ Cv,
                                               const float* __restrict__ xres,
                                               int ldc, int K,
                                               int gA, int gW, int gC) {
  const int g = blockIdx.z;
  A  += (size_t)g * gA;
  WT += (size_t)g * gW;
  const int lane = threadIdx.x & 63;
  const int w = threadIdx.x >> 6, wy = w >> 1, wx = w & 1;
  const int col = lane & 15, quad = lane >> 4;
  const int bm = blockIdx.y * 64, bn = blockIdx.x * 64;
  f32x4 acc[2][2];
#pragma unroll
  for (int a = 0; a < 2; a++)
#pragma unroll
    for (int b = 0; b < 2; b++) acc[a][b] = (f32x4){0.f, 0.f, 0.f, 0.f};
  const bf16* Ap = A + (size_t)(bm + wy * 32 + col) * lda + quad * 8;
  const bf16* Bp = WT + (size_t)(bn + wx * 32 + col) * K + quad * 8;
  for (int k0 = 0; k0 < K; k0 += 32) {
    short8 a0 = *(const short8*)(Ap + k0);
    short8 a1 = *(const short8*)(Ap + (size_t)16 * lda + k0);
    short8 b0 = *(const short8*)(Bp + k0);
    short8 b1 = *(const short8*)(Bp + (size_t)16 * K + k0);
    acc[0][0] = __builtin_amdgcn_mfma_f32_16x16x32_bf16(a0, b0, acc[0][0], 0, 0, 0);
    acc[0][1] = __builtin_amdgcn_mfma_f32_16x16x32_bf16(a0, b1, acc[0][1], 0, 0, 0);
    acc[1][0] = __builtin_amdgcn_mfma_f32_16x16x32_bf16(a1, b0, acc[1][0], 0, 0, 0);
    acc[1][1] = __builtin_amdgcn_mfma_f32_16x16x32_bf16(a1, b1, acc[1][1], 0, 0, 0);
  }
#pragma unroll
  for (int mt = 0; mt < 2; mt++) {
#pragma unroll
    for (int nt = 0; nt < 2; nt++) {
      const int n = bn + wx * 32 + nt * 16 + col;
      const int mrow0 = bm + wy * 32 + mt * 16 + quad * 4;
      float bs = bias ? bias[n] : 0.f;
      if (STORE == 1) {
        bf16* C = (bf16*)Cv + (size_t)g * gC;
        ushort4 pk;
        pk.x = f2bu(acc[mt][nt][0] + bs); pk.y = f2bu(acc[mt][nt][1] + bs);
        pk.z = f2bu(acc[mt][nt][2] + bs); pk.w = f2bu(acc[mt][nt][3] + bs);
        *(ushort4*)(C + (size_t)n * 4096 + mrow0) = pk;
      } else if (STORE == 2) {
        float* O = (float*)Cv + (size_t)g * gC;
#pragma unroll
        for (int r = 0; r < 4; r++) {
          size_t gi = (size_t)(mrow0 + r) * ldc + n;
          O[gi] = acc[mt][nt][r] + bs + xres[gi];
        }
      } else {
        bf16* C = (bf16*)Cv + (size_t)g * gC;
#pragma unroll
        for (int r = 0; r < 4; r++) {
          float v = acc[mt][nt][r] + bs;
          if (ACT == 1) v = v / (1.f + expf(-v));  // silu
          C[(size_t)(mrow0 + r) * ldc + n] = f2b(v);
        }
      }
    }
  }
}

// ---------------- MFMA causal conv1d: 4 shifted K-passes, fused bias+silu ----------------
__global__ void __launch_bounds__(256) k_conv_mfma(const bf16* __restrict__ a,
                                                   const bf16* __restrict__ wct,
                                                   const float* __restrict__ cb,
                                                   bf16* __restrict__ qk) {
  const int lane = threadIdx.x & 63;
  const int w = threadIdx.x >> 6, wy = w >> 1, wx = w & 1;
  const int col = lane & 15, quad = lane >> 4;
  const int bm = blockIdx.y * 64, bn = blockIdx.x * 64;
  const int b_ = bm >> 11;
  const int t0 = (bm & 2047) + wy * 32 + col;
  f32x4 acc[2][2];
#pragma unroll
  for (int x = 0; x < 2; x++)
#pragma unroll
    for (int y = 0; y < 2; y++) acc[x][y] = (f32x4){0.f, 0.f, 0.f, 0.f};
  const bf16* Bp = wct + (size_t)(bn + wx * 32 + col) * 1024 + quad * 8;
  for (int kk = 0; kk < 4; kk++) {
    const int ts0 = t0 - 3 + kk;
    const int ts1 = ts0 + 16;
    const bf16* ap0 = a + ((size_t)(b_ << 11) + ts0) * DIM2X + quad * 8;
    const bf16* ap1 = a + ((size_t)(b_ << 11) + ts1) * DIM2X + quad * 8;
    const bf16* bp = Bp + (size_t)kk * 1048576;
    for (int k0 = 0; k0 < DIM2X; k0 += 32) {
      short8 a0 = {0, 0, 0, 0, 0, 0, 0, 0};
      if (ts0 >= 0) a0 = *(const short8*)(ap0 + k0);
      short8 a1 = *(const short8*)(ap1 + k0);
      short8 b0 = *(const short8*)(bp + k0);
      short8 b1 = *(const short8*)(bp + (size_t)16 * 1024 + k0);
      acc[0][0] = __builtin_amdgcn_mfma_f32_16x16x32_bf16(a0, b0, acc[0][0], 0, 0, 0);
      acc[0][1] = __builtin_amdgcn_mfma_f32_16x16x32_bf16(a0, b1, acc[0][1], 0, 0, 0);
      acc[1][0] = __builtin_amdgcn_mfma_f32_16x16x32_bf16(a1, b0, acc[1][0], 0, 0, 0);
      acc[1][1] = __builtin_amdgcn_mfma_f32_16x16x32_bf16(a1, b1, acc[1][1], 0, 0, 0);
    }
  }
#pragma unroll
  for (int mt = 0; mt < 2; mt++) {
#pragma unroll
    for (int nt = 0; nt < 2; nt++) {
      const int n = bn + wx * 32 + nt * 16 + col;
      const int mrow0 = bm + wy * 32 + mt * 16 + quad * 4;
      const float bs = cb[n];
#pragma unroll
      for (int r = 0; r < 4; r++) {
        float v = acc[mt][nt][r] + bs;
        v = v / (1.f + expf(-v));  // silu
        qk[(size_t)(mrow0 + r) * DIM2X + n] = f2b(v);
      }
    }
  }
}

// ---------------- gate GEMV ----------------
__global__ void __launch_bounds__(256) k_gates(const bf16* __restrict__ q, const bf16* __restrict__ kk,
                                               const float* __restrict__ wi, const float* __restrict__ wib,
                                               const float* __restrict__ wf, const float* __restrict__ wfb,
                                               float* __restrict__ it, float* __restrict__ ft) {
  int gid  = blockIdx.x * 4 + (threadIdx.x >> 6);
  int lane = threadIdx.x & 63;
  int which = gid >> 12;
  int m = gid & 4095;
  const bf16* row = (which ? kk : q) + (size_t)m * DIM2X;
  const float* w = which ? wf : wi;
  float s[8] = {0, 0, 0, 0, 0, 0, 0, 0};
  for (int d = lane; d < DIM2X; d += 64) {
    float xv = b2f(row[d]);
    const float4* wp = (const float4*)(w + d * 8);
    float4 w0 = wp[0], w1 = wp[1];
    s[0] += xv * w0.x; s[1] += xv * w0.y; s[2] += xv * w0.z; s[3] += xv * w0.w;
    s[4] += xv * w1.x; s[5] += xv * w1.y; s[6] += xv * w1.z; s[7] += xv * w1.w;
  }
#pragma unroll
  for (int off = 32; off; off >>= 1) {
#pragma unroll
    for (int h = 0; h < 8; h++) s[h] += __shfl_xor(s[h], off);
  }
  if (lane == 0) {
    int b_ = m >> 11, tt = m & 2047;
    const float* wb = which ? wfb : wib;
    float* dst = which ? ft : it;
#pragma unroll
    for (int h = 0; h < 8; h++)
      dst[((size_t)(b_ * NHEADS + h)) * SEQ + tt] = s[h] + wb[h];
  }
}

// ---------------- per-(b,h) scan ----------------
__global__ void __launch_bounds__(256) k_scan(const float* __restrict__ it, const float* __restrict__ ft,
                                              float* __restrict__ cs, float* __restrict__ md) {
  const int bh = blockIdx.x;
  const int t  = threadIdx.x;
  const float* fr = ft + (size_t)bh * SEQ;
  const float* ir = it + (size_t)bh * SEQ;
  float* csr = cs + (size_t)bh * SEQ;
  float* mdr = md + (size_t)bh * SEQ;
  __shared__ float tmp[256];
  float loc[8]; float run = 0.f;
#pragma unroll
  for (int j = 0; j < 8; j++) {
    float xv = fr[t * 8 + j];
    float ls = fminf(xv, 0.f) - log1pf(expf(-fabsf(xv)));
    run += ls; loc[j] = run;
  }
  tmp[t] = run;
  __syncthreads();
  for (int off = 1; off < 256; off <<= 1) {
    float add = (t >= off) ? tmp[t - off] : 0.f;
    __syncthreads();
    tmp[t] += add;
    __syncthreads();
  }
  float exc = (t == 0) ? 0.f : tmp[t - 1];
  float csv[8];
#pragma unroll
  for (int j = 0; j < 8; j++) { csv[j] = loc[j] + exc; csr[t * 8 + j] = csv[j]; }
  __syncthreads();
  float rmax = -INFINITY; float gm[8];
#pragma unroll
  for (int j = 0; j < 8; j++) {
    float gv = ir[t * 8 + j] - csv[j];
    rmax = fmaxf(rmax, gv); gm[j] = rmax;
  }
  tmp[t] = rmax;
  __syncthreads();
  for (int off = 1; off < 256; off <<= 1) {
    float other = (t >= off) ? tmp[t - off] : -INFINITY;
    __syncthreads();
    tmp[t] = fmaxf(tmp[t], other);
    __syncthreads();
  }
  float emax = (t == 0) ? -INFINITY : tmp[t - 1];
#pragma unroll
  for (int j = 0; j < 8; j++) mdr[t * 8 + j] = csv[j] + fmaxf(gm[j], emax);
}

// ---------------- MFMA causal attention, SPLIT-J: 4 waves/block, in-block combine ----------------
// Partial sums over disjoint j-ranges are directly additive because md (exact row max)
// is precomputed — no online-softmax merge. Wave w handles j0p = (w + 4p)*32.
__global__ void __launch_bounds__(256) k_attn_mfma(const bf16* __restrict__ qh,
                                                   const bf16* __restrict__ kh,
                                                   const bf16* __restrict__ vt,
                                                   const float* __restrict__ cs,
                                                   const float* __restrict__ md,
                                                   const float* __restrict__ itl,
                                                   bf16* __restrict__ Hout) {
  const int bh = blockIdx.y, b_ = bh >> 3, h = bh & 7;
  const int it16 = 127 - blockIdx.x;          // heavy tiles dispatched first
  const int i0 = it16 * 16;
  const int w = threadIdx.x >> 6;             // wave 0..3
  const int lane = threadIdx.x & 63;
  const int col = lane & 15, quad = lane >> 4;
  __shared__ __align__(16) bf16 Sc[4][16][40];
  __shared__ float redbuf[4][64][36];         // 32 accpv + 4 rs per lane per wave

  const size_t baseQK = ((size_t)b_ * SEQ) * DIM2X + (size_t)h * HDIM;
  const float* csp = cs + (size_t)bh * SEQ;
  const float* mdp = md + (size_t)bh * SEQ;
  const float* itp = itl + (size_t)bh * SEQ;

  short8 qf[4];
#pragma unroll
  for (int kc = 0; kc < 4; kc++)
    qf[kc] = *(const short8*)(qh + baseQK + (size_t)(i0 + col) * DIM2X + kc * 32 + quad * 8);

  float cs_i[4], md_i[4];
#pragma unroll
  for (int r = 0; r < 4; r++) {
    int i = i0 + quad * 4 + r;
    cs_i[r] = csp[i]; md_i[r] = mdp[i];
  }

  f32x4 accpv[8];
#pragma unroll
  for (int nb = 0; nb < 8; nb++) accpv[nb] = (f32x4){0.f, 0.f, 0.f, 0.f};
  float rs[4] = {0.f, 0.f, 0.f, 0.f};

  const size_t vtb = (size_t)(h * HDIM) * 4096 + (size_t)b_ * SEQ;

  const int P = i0 / 128 + 1;                 // uniform trip count across all 4 waves
  for (int p = 0; p < P; p++) {
    const int j0p = (w + p * 4) * 32;
    const bool act = (j0p <= i0);
    __syncthreads();                          // uniform: guards Sc reuse
    if (act) {
#pragma unroll
      for (int jt = 0; jt < 2; jt++) {
        const int j0 = j0p + jt * 16;
        float sv[4] = {0.f, 0.f, 0.f, 0.f};
        if (j0 <= i0 + 15) {
          f32x4 aq = (f32x4){0.f, 0.f, 0.f, 0.f};
#pragma unroll
          for (int kc = 0; kc < 4; kc++) {
            short8 bk = *(const short8*)(kh + baseQK + (size_t)(j0 + col) * DIM2X + kc * 32 + quad * 8);
            aq = __builtin_amdgcn_mfma_f32_16x16x32_bf16(qf[kc], bk, aq, 0, 0, 0);
          }
          const int j = j0 + col;
          const float gj = itp[j] - csp[j];
#pragma unroll
          for (int r = 0; r < 4; r++) {
            const int i = i0 + quad * 4 + r;
            float s = (j <= i) ? satexp(cs_i[r] + gj - md_i[r]) * aq[r] * (1.f / 32.f) : 0.f;
            sv[r] = s; rs[r] += s;
          }
        }
#pragma unroll
        for (int r = 0; r < 4; r++) Sc[w][quad * 4 + r][jt * 16 + col] = f2b(sv[r]);
      }
    }
    __syncthreads();                          // uniform: Sc writes visible (own-wave read)
    if (act) {
      short8 af = *(const short8*)(&Sc[w][col][quad * 8]);
#pragma unroll
      for (int nb = 0; nb < 8; nb++) {
        short8 bv = *(const short8*)(vt + vtb + (size_t)(nb * 16 + col) * 4096 + j0p + quad * 8);
        accpv[nb] = __builtin_amdgcn_mfma_f32_16x16x32_bf16(af, bv, accpv[nb], 0, 0, 0);
      }
    }
  }
  // wave-local row-sum reduction (rs uniform per 16-lane group afterwards)
#pragma unroll
  for (int r = 0; r < 4; r++) {
    float v = rs[r];
    v += __shfl_xor(v, 1); v += __shfl_xor(v, 2);
    v += __shfl_xor(v, 4); v += __shfl_xor(v, 8);
    rs[r] = v;
  }
  // dump partials to LDS
#pragma unroll
  for (int nb = 0; nb < 8; nb++)
#pragma unroll
    for (int r = 0; r < 4; r++) redbuf[w][lane][nb * 4 + r] = accpv[nb][r];
#pragma unroll
  for (int r = 0; r < 4; r++) redbuf[w][lane][32 + r] = rs[r];
  __syncthreads();
  if (w == 0) {
    float tot[36];
#pragma unroll
    for (int e = 0; e < 36; e++)
      tot[e] = redbuf[0][lane][e] + redbuf[1][lane][e] + redbuf[2][lane][e] + redbuf[3][lane][e];
    float inv[4];
#pragma unroll
    for (int r = 0; r < 4; r++) {
      float maxit = fmaxf(fabsf(tot[32 + r]), satexp(-md_i[r]));
      inv[r] = 1.f / (maxit + 1e-8f);
    }
#pragma unroll
    for (int nb = 0; nb < 8; nb++)
#pragma unroll
      for (int r = 0; r < 4; r++)
        Hout[baseQK + (size_t)(i0 + quad * 4 + r) * DIM2X + nb * 16 + col] = f2b(tot[nb * 4 + r] * inv[r]);
  }
}

// ---------------- GroupNorm(per-head over 128) + skip*qk then *bgate ----------------
__global__ void __launch_bounds__(256) k_gnorm(const bf16* __restrict__ H, const bf16* __restrict__ qk,
                                               const bf16* __restrict__ bg,
                                               const float* __restrict__ gw, const float* __restrict__ gb,
                                               const float* __restrict__ skip, bf16* __restrict__ pre) {
  int gid  = blockIdx.x * 4 + (threadIdx.x >> 6);
  int lane = threadIdx.x & 63;
  int m = gid >> 3, h = gid & 7;
  const bf16* Hr = H + (size_t)m * DIM2X + (size_t)h * HDIM;
  float v0 = b2f(Hr[lane]), v1 = b2f(Hr[lane + 64]);
  float s = v0 + v1, sq = v0 * v0 + v1 * v1;
#pragma unroll
  for (int off = 32; off; off >>= 1) { s += __shfl_xor(s, off); sq += __shfl_xor(sq, off); }
  float mu  = s * (1.f / 128.f);
  float var = sq * (1.f / 128.f) - mu * mu;
  float rs  = rsqrtf(var + EPSF);
#pragma unroll
  for (int e = 0; e < 2; e++) {
    int c = lane + e * 64;
    int col = h * HDIM + c;
    float v = e ? v1 : v0;
    float hn = (v - mu) * rs * gw[col] + gb[col];
    size_t gidx = (size_t)m * DIM2X + col;
    pre[gidx] = f2b((hn + skip[col] * b2f(qk[gidx])) * b2f(bg[gidx]));
  }
}

extern "C" void kernel_launch(void* const* d_in, const int* in_sizes, int n_in,
                              void* d_out, int out_size, void* d_ws, size_t ws_size,
                              hipStream_t stream) {
  const float* x     = (const float*)d_in[0];
  const float* ln_w  = (const float*)d_in[1];
  const float* ln_b  = (const float*)d_in[2];
  const float* mlp1w = (const float*)d_in[3];
  const float* mlp1b = (const float*)d_in[4];
  const float* mlp2w = (const float*)d_in[5];
  const float* mlp2b = (const float*)d_in[6];
  const float* convw = (const float*)d_in[7];
  const float* convb = (const float*)d_in[8];
  const float* bqw   = (const float*)d_in[9];
  const float* bkw   = (const float*)d_in[10];
  const float* bvw   = (const float*)d_in[11];
  const float* wqw   = (const float*)d_in[12];
  const float* wqb   = (const float*)d_in[13];
  const float* wkw   = (const float*)d_in[14];
  const float* wkb   = (const float*)d_in[15];
  const float* wvw   = (const float*)d_in[16];
  const float* wvb   = (const float*)d_in[17];
  const float* wiw   = (const float*)d_in[18];
  const float* wib   = (const float*)d_in[19];
  const float* wfw   = (const float*)d_in[20];
  const float* wfb   = (const float*)d_in[21];
  const float* gnw   = (const float*)d_in[22];
  const float* gnb   = (const float*)d_in[23];
  const float* skip  = (const float*)d_in[24];
  const float* finw  = (const float*)d_in[25];
  const float* finb  = (const float*)d_in[26];
  float* out = (float*)d_out;

  float* GA  = (float*)d_ws;
  float* ITb = GA;
  float* FTb = GA + 32768;
  float* CSb = GA + 65536;
  float* MDb = GA + 98304;
  const size_t SLOT = 4u * 1024u * 1024u;
  bf16* S0 = (bf16*)((char*)d_ws + (1 << 20));
  bf16* S1 = S0 + SLOT;
  bf16* S2 = S1 + SLOT;
  bf16* S3 = S2 + SLOT;
  bf16* S4 = S3 + SLOT;
  bf16* S5 = S4 + SLOT;
  bf16* S6 = S5 + SLOT;
  bf16 *LN = S0, *A_ = S1, *BG = S2, *QKb = S3, *Qb = S4, *Kb = S5, *Vb = S6;
  bf16 *QH = S0, *KH = S1, *VT = S4, *Hb = S5, *PRE = S6;
  bf16* WTb   = S6 + SLOT;
  bf16* mlp1T = WTb;
  bf16* mlp2T = WTb + 524288;
  bf16* convT = WTb + 1048576;
  bf16* bqT   = WTb + 5242880;
  bf16* bkT   = bqT + 262144;
  bf16* bvT   = bkT + 262144;
  bf16* wqT   = bvT + 262144;
  bf16* wkT   = wqT + 1048576;
  bf16* wvT   = wkT + 1048576;
  bf16* finT  = wvT + 1048576;

  k_castT<<<dim3(32, 16), 256, 0, stream>>>(mlp1w, mlp1T, DIMX, DIM2X, 0, 0);
  k_castT<<<dim3(32, 16), 256, 0, stream>>>(mlp2w, mlp2T, DIMX, DIM2X, 0, 0);
  k_convwT<<<16384, 256, 0, stream>>>(convw, convT);
  k_castT<<<dim3(8, 8, 4), 256, 0, stream>>>(bqw, bqT, 256, 256, 65536, 65536);
  k_castT<<<dim3(8, 8, 4), 256, 0, stream>>>(bkw, bkT, 256, 256, 65536, 65536);
  k_castT<<<dim3(8, 8, 4), 256, 0, stream>>>(bvw, bvT, 256, 256, 65536, 65536);
  k_castT<<<dim3(32, 32), 256, 0, stream>>>(wqw, wqT, DIM2X, DIM2X, 0, 0);
  k_castT<<<dim3(32, 32), 256, 0, stream>>>(wkw, wkT, DIM2X, DIM2X, 0, 0);
  k_castT<<<dim3(32, 32), 256, 0, stream>>>(wvw, wvT, DIM2X, DIM2X, 0, 0);
  k_castT<<<dim3(16, 32), 256, 0, stream>>>(finw, finT, DIM2X, DIMX, 0, 0);

  k_layernorm<<<1024, 256, 0, stream>>>(x, ln_w, ln_b, LN);
  k_mgemm<0,0><<<dim3(16, 64), 256, 0, stream>>>(LN, DIMX, mlp1T, mlp1b, A_, nullptr, DIM2X, DIMX, 0, 0, 0);
  k_mgemm<1,0><<<dim3(16, 64), 256, 0, stream>>>(LN, DIMX, mlp2T, mlp2b, BG, nullptr, DIM2X, DIMX, 0, 0, 0);
  k_conv_mfma<<<dim3(16, 64), 256, 0, stream>>>(A_, convT, convb, QKb);
  k_mgemm<0,0><<<dim3(4, 64, 4), 256, 0, stream>>>(QKb, DIM2X, bqT, nullptr, Qb, nullptr, DIM2X, 256, 256, 65536, 256);
  k_mgemm<0,0><<<dim3(4, 64, 4), 256, 0, stream>>>(QKb, DIM2X, bkT, nullptr, Kb, nullptr, DIM2X, 256, 256, 65536, 256);
  k_mgemm<0,0><<<dim3(4, 64, 4), 256, 0, stream>>>(A_,  DIM2X, bvT, nullptr, Vb, nullptr, DIM2X, 256, 256, 65536, 256);
  k_gates<<<2048, 256, 0, stream>>>(Qb, Kb, wiw, wib, wfw, wfb, ITb, FTb);
  k_scan<<<16, 256, 0, stream>>>(ITb, FTb, CSb, MDb);
  k_mgemm<0,0><<<dim3(16, 64), 256, 0, stream>>>(Qb, DIM2X, wqT, wqb, QH, nullptr, DIM2X, DIM2X, 0, 0, 0);
  k_mgemm<0,0><<<dim3(16, 64), 256, 0, stream>>>(Kb, DIM2X, wkT, wkb, KH, nullptr, DIM2X, DIM2X, 0, 0, 0);
  k_mgemm<0,1><<<dim3(16, 64), 256, 0, stream>>>(Vb, DIM2X, wvT, wvb, VT, nullptr, 0, DIM2X, 0, 0, 0);  // V^T
  k_attn_mfma<<<dim3(128, 16), 256, 0, stream>>>(QH, KH, VT, CSb, MDb, ITb, Hb);
  k_gnorm<<<8192, 256, 0, stream>>>(Hb, QKb, BG, gnw, gnb, skip, PRE);
  k_mgemm<0,2><<<dim3(8, 64), 256, 0, stream>>>(PRE, DIM2X, finT, finb, out, x, DIMX, DIM2X, 0, 0, 0);
}